// Round 9
// baseline (521.447 us; speedup 1.0000x reference)
//
#include <hip/hip_runtime.h>
#include <stdint.h>

#define NDIM 64
#define SCAN_ELEMS 2048   // elements per scan block (256 thr x 8)
#define NCHK 16           // edge chunks
#define NGRP 8            // node-range groups
#define RMAX 6272         // max nodes per group (ceil(50000/8)=6250)

typedef unsigned int uint;
typedef unsigned short ushort;

// round-to-nearest-even fp32 -> bf16 (pair packed into a uint)
__device__ __forceinline__ uint f2bf2(float a, float b) {
  uint ua = __float_as_uint(a);
  uint ub = __float_as_uint(b);
  ua += 0x7fffu + ((ua >> 16) & 1u);
  ub += 0x7fffu + ((ub >> 16) & 1u);
  return (ua >> 16) | (ub & 0xffff0000u);
}

// ---------------- weight transpose (k-major) ----------------
__global__ __launch_bounds__(256) void transpose_kernel(
    const float* __restrict__ fw, const float* __restrict__ rootw,
    const float* __restrict__ lin1, const float* __restrict__ lin2,
    float* __restrict__ fwT, float* __restrict__ wrT,
    float* __restrict__ w1T, float* __restrict__ w2T) {
  int e = blockIdx.x * 256 + threadIdx.x;
  if (e < 16384) {
    int o = e >> 8, k = e & 255;
    fwT[k * 64 + o] = fw[e];
  }
  int e2 = e - 16384;
  if (e2 >= 0 && e2 < 12288) {
    int l = e2 >> 12, r = e2 & 4095;
    int o = r >> 6, k = r & 63;
    size_t t = (size_t)l * 4096 + k * 64 + o;
    wrT[t] = rootw[e2];
    w1T[t] = lin1[e2];
    w2T[t] = lin2[e2];
  }
}

// ---------------- x -> bf16 table ----------------
__global__ __launch_bounds__(256) void convx_kernel(
    const float* __restrict__ x, uint* __restrict__ xb, int n4) {
  int e = blockIdx.x * 256 + threadIdx.x;
  if (e >= n4) return;
  float4 v = ((const float4*)x)[e];
  uint2 o;
  o.x = f2bf2(v.x, v.y);
  o.y = f2bf2(v.z, v.w);
  ((uint2*)xb)[e] = o;
}

// ---------------- CSR build: atomic-free chunked counting sort ----------------
__global__ __launch_bounds__(256) void hist_kernel(
    const int* __restrict__ src, const int* __restrict__ dst,
    int* __restrict__ Hd, int* __restrict__ Hs, int E, int N, int chunk) {
  int c = blockIdx.x, g = blockIdx.y;
  int lo = (int)((long long)N * g / NGRP);
  int hi = (int)((long long)N * (g + 1) / NGRP);
  int range = hi - lo;
  __shared__ int cntd[RMAX];
  __shared__ int cnts[RMAX];
  for (int i = threadIdx.x; i < range; i += 256) { cntd[i] = 0; cnts[i] = 0; }
  __syncthreads();
  int e0 = c * chunk, e1 = min(E, e0 + chunk);
  for (int e = e0 + (int)threadIdx.x * 4; e < e1; e += 1024) {
    if (e + 4 <= e1) {
      int4 s4 = *(const int4*)(src + e);
      int4 d4 = *(const int4*)(dst + e);
      if (d4.x >= lo && d4.x < hi) atomicAdd(&cntd[d4.x - lo], 1);
      if (d4.y >= lo && d4.y < hi) atomicAdd(&cntd[d4.y - lo], 1);
      if (d4.z >= lo && d4.z < hi) atomicAdd(&cntd[d4.z - lo], 1);
      if (d4.w >= lo && d4.w < hi) atomicAdd(&cntd[d4.w - lo], 1);
      if (s4.x >= lo && s4.x < hi) atomicAdd(&cnts[s4.x - lo], 1);
      if (s4.y >= lo && s4.y < hi) atomicAdd(&cnts[s4.y - lo], 1);
      if (s4.z >= lo && s4.z < hi) atomicAdd(&cnts[s4.z - lo], 1);
      if (s4.w >= lo && s4.w < hi) atomicAdd(&cnts[s4.w - lo], 1);
    } else {
      for (int k = e; k < e1; ++k) {
        int s = src[k], d = dst[k];
        if (d >= lo && d < hi) atomicAdd(&cntd[d - lo], 1);
        if (s >= lo && s < hi) atomicAdd(&cnts[s - lo], 1);
      }
    }
  }
  __syncthreads();
  for (int i = threadIdx.x; i < range; i += 256) {
    Hd[(size_t)c * N + lo + i] = cntd[i];
    Hs[(size_t)c * N + lo + i] = cnts[i];
  }
}

__global__ __launch_bounds__(256) void degsum_kernel(
    const int* __restrict__ Hd, const int* __restrict__ Hs,
    int* __restrict__ deg_d, int* __restrict__ deg_s, int N) {
  int n = blockIdx.x * 256 + threadIdx.x;
  if (n >= N) return;
  int sd = 0, ss = 0;
#pragma unroll
  for (int c = 0; c < NCHK; ++c) {
    sd += Hd[(size_t)c * N + n];
    ss += Hs[(size_t)c * N + n];
  }
  deg_d[n] = sd;
  deg_s[n] = ss;
}

__global__ __launch_bounds__(256) void scan_partial(
    const int* __restrict__ deg_d, const int* __restrict__ deg_s,
    int* __restrict__ bsum, int n, int nb) {
  const int* deg = (blockIdx.y == 0) ? deg_d : deg_s;
  int tid = threadIdx.x;
  int base = blockIdx.x * SCAN_ELEMS;
  int s = 0;
#pragma unroll
  for (int j = 0; j < 8; ++j) {
    int i = base + j * 256 + tid;
    if (i < n) s += deg[i];
  }
#pragma unroll
  for (int off = 1; off < 64; off <<= 1) s += __shfl_xor(s, off);
  __shared__ int ws[4];
  if ((tid & 63) == 0) ws[tid >> 6] = s;
  __syncthreads();
  if (tid == 0) bsum[blockIdx.y * nb + blockIdx.x] = ws[0] + ws[1] + ws[2] + ws[3];
}

__global__ __launch_bounds__(256) void scan_bsum(int* __restrict__ bsum, int nb) {
  __shared__ int sh[256];
  int tid = threadIdx.x;
  for (int h = 0; h < 2; ++h) {
    int v = (tid < nb) ? bsum[h * nb + tid] : 0;
    sh[tid] = v;
    __syncthreads();
    for (int off = 1; off < 256; off <<= 1) {
      int t = (tid >= off) ? sh[tid - off] : 0;
      __syncthreads();
      sh[tid] += t;
      __syncthreads();
    }
    if (tid < nb) bsum[h * nb + tid] = sh[tid] - v;  // exclusive
    __syncthreads();
  }
}

__global__ __launch_bounds__(256) void scan_final(
    const int* __restrict__ deg_d, const int* __restrict__ deg_s,
    const int* __restrict__ bsum,
    int* __restrict__ row_d, int* __restrict__ row_s, int n, int nb) {
  const int* deg = (blockIdx.y == 0) ? deg_d : deg_s;
  int* row = (blockIdx.y == 0) ? row_d : row_s;
  int tid = threadIdx.x;
  int lane = tid & 63;
  int e0 = blockIdx.x * SCAN_ELEMS + tid * 8;
  int v[8];
  int s = 0;
#pragma unroll
  for (int j = 0; j < 8; ++j) {
    int i = e0 + j;
    v[j] = (i < n) ? deg[i] : 0;
    s += v[j];
  }
  int incl = s;
#pragma unroll
  for (int off = 1; off < 64; off <<= 1) {
    int t = __shfl_up(incl, off);
    if (lane >= off) incl += t;
  }
  __shared__ int wsum[4];
  if (lane == 63) wsum[tid >> 6] = incl;
  __syncthreads();
  int woff = 0;
  int w = tid >> 6;
  for (int k = 0; k < 4; ++k)
    if (k < w) woff += wsum[k];
  int run = incl - s + woff + bsum[blockIdx.y * nb + blockIdx.x];
#pragma unroll
  for (int j = 0; j < 8; ++j) {
    int i = e0 + j;
    if (i <= n) row[i] = run;
    run += v[j];
  }
}

__global__ __launch_bounds__(256) void cursor_kernel(
    int* __restrict__ Hd, int* __restrict__ Hs,
    const int* __restrict__ row_d, const int* __restrict__ row_s, int N) {
  int n = blockIdx.x * 256 + threadIdx.x;
  if (n >= N) return;
  int rd = row_d[n], rs = row_s[n];
#pragma unroll
  for (int c = 0; c < NCHK; ++c) {
    int t = Hd[(size_t)c * N + n]; Hd[(size_t)c * N + n] = rd; rd += t;
    t = Hs[(size_t)c * N + n];     Hs[(size_t)c * N + n] = rs; rs += t;
  }
}

// scatter: grid (x=g, y=c) so linear_id%8 == g -> each col region has a
// single-writer XCD (kills write-line ping-pong). Edge chunks stay L3-hot.
__global__ __launch_bounds__(256) void scatter_kernel(
    const int* __restrict__ src, const int* __restrict__ dst,
    const int* __restrict__ Hd, const int* __restrict__ Hs,
    int* __restrict__ col_d, int* __restrict__ col_s, int E, int N, int chunk) {
  int g = blockIdx.x, c = blockIdx.y;
  int lo = (int)((long long)N * g / NGRP);
  int hi = (int)((long long)N * (g + 1) / NGRP);
  int range = hi - lo;
  __shared__ int curd[RMAX];
  __shared__ int curs[RMAX];
  for (int i = threadIdx.x; i < range; i += 256) {
    curd[i] = Hd[(size_t)c * N + lo + i];
    curs[i] = Hs[(size_t)c * N + lo + i];
  }
  __syncthreads();
  int e0 = c * chunk, e1 = min(E, e0 + chunk);
  for (int e = e0 + (int)threadIdx.x * 4; e < e1; e += 1024) {
    if (e + 4 <= e1) {
      int4 s4 = *(const int4*)(src + e);
      int4 d4 = *(const int4*)(dst + e);
      if (d4.x >= lo && d4.x < hi) { int p = atomicAdd(&curd[d4.x - lo], 1); col_d[p] = s4.x; }
      if (d4.y >= lo && d4.y < hi) { int p = atomicAdd(&curd[d4.y - lo], 1); col_d[p] = s4.y; }
      if (d4.z >= lo && d4.z < hi) { int p = atomicAdd(&curd[d4.z - lo], 1); col_d[p] = s4.z; }
      if (d4.w >= lo && d4.w < hi) { int p = atomicAdd(&curd[d4.w - lo], 1); col_d[p] = s4.w; }
      if (s4.x >= lo && s4.x < hi) { int p = atomicAdd(&curs[s4.x - lo], 1); col_s[p] = d4.x; }
      if (s4.y >= lo && s4.y < hi) { int p = atomicAdd(&curs[s4.y - lo], 1); col_s[p] = d4.y; }
      if (s4.z >= lo && s4.z < hi) { int p = atomicAdd(&curs[s4.z - lo], 1); col_s[p] = d4.z; }
      if (s4.w >= lo && s4.w < hi) { int p = atomicAdd(&curs[s4.w - lo], 1); col_s[p] = d4.w; }
    } else {
      for (int k = e; k < e1; ++k) {
        int s = src[k], d = dst[k];
        if (d >= lo && d < hi) { int p = atomicAdd(&curd[d - lo], 1); col_d[p] = s; }
        if (s >= lo && s < hi) { int p = atomicAdd(&curs[s - lo], 1); col_s[p] = d; }
      }
    }
  }
}

// ---------------- aggregation (bf16, feature-split so table half is L2-resident) --------
// grid y in [0,4): dir = y>>1, feature-half = y&1. Active sub-table = 3.2 MB
// (one 64B line per node) < 4 MB/XCD L2. Lane quarter q handles neighbor p+q,
// fl = feature pair. Reduce across quarters with shfl_xor(16,32).

__global__ __launch_bounds__(256) void agg4_kernel(
    const ushort* __restrict__ hB,
    const int* __restrict__ row_d, const int* __restrict__ col_d, float* __restrict__ g1,
    const int* __restrict__ row_s, const int* __restrict__ col_s, float* __restrict__ g2,
    int N) {
  int dir = blockIdx.y >> 1;
  int fh  = blockIdx.y & 1;
  const int* row = dir ? row_s : row_d;
  const int* col = dir ? col_s : col_d;
  float* outp = dir ? g2 : g1;
  int wid = blockIdx.x * 4 + (threadIdx.x >> 6);
  int lane = threadIdx.x & 63;
  int q = lane >> 4;
  int fl = lane & 15;
  if (wid >= N) return;
  int s0 = row[wid], s1 = row[wid + 1];
  const ushort* tab = hB + fh * 32 + fl * 2;
  float ax0 = 0.f, ay0 = 0.f, ax1 = 0.f, ay1 = 0.f;
  int p = s0;
  for (; p + 8 <= s1; p += 8) {
    int n0 = col[p + q];
    int n1 = col[p + 4 + q];
    uint u0 = *(const uint*)(tab + (size_t)n0 * 64);
    uint u1 = *(const uint*)(tab + (size_t)n1 * 64);
    ax0 += __uint_as_float(u0 << 16);
    ay0 += __uint_as_float(u0 & 0xffff0000u);
    ax1 += __uint_as_float(u1 << 16);
    ay1 += __uint_as_float(u1 & 0xffff0000u);
  }
  if (p + q < s1) {
    int n = col[p + q];
    uint u = *(const uint*)(tab + (size_t)n * 64);
    ax0 += __uint_as_float(u << 16);
    ay0 += __uint_as_float(u & 0xffff0000u);
  }
  if (p + 4 + q < s1) {
    int n = col[p + 4 + q];
    uint u = *(const uint*)(tab + (size_t)n * 64);
    ax1 += __uint_as_float(u << 16);
    ay1 += __uint_as_float(u & 0xffff0000u);
  }
  float sx = ax0 + ax1, sy = ay0 + ay1;
  sx += __shfl_xor(sx, 16); sy += __shfl_xor(sy, 16);
  sx += __shfl_xor(sx, 32); sy += __shfl_xor(sy, 32);
  int cnt = s1 - s0;
  float inv = cnt > 0 ? 1.f / (float)cnt : 0.f;
  if (q == 0) {
    float2 v; v.x = sx * inv; v.y = sy * inv;
    ((float2*)(outp + (size_t)wid * NDIM + fh * 32))[fl] = v;
  }
}

// ---------------- combine: 64-node LDS tile, lane=node, wave=16 outputs ----------------

__global__ __launch_bounds__(256, 3) void combine_kernel(
    const float* __restrict__ h, const float* __restrict__ g1,
    const float* __restrict__ g2, const float* __restrict__ wrT,
    const float* __restrict__ w1T, const float* __restrict__ w2T,
    const float* __restrict__ bias, float* __restrict__ hout,
    ushort* __restrict__ hbout, int N) {
  __shared__ float Ht[64][65];
  __shared__ float G1t[64][65];
  __shared__ float G2t[64][65];
  int tid = threadIdx.x;
  int n0 = blockIdx.x * 64;
  int r = tid >> 2;
  bool ok = (n0 + r) < N;
  const float4* hp = (const float4*)(h  + (size_t)(n0 + r) * NDIM);
  const float4* q1 = (const float4*)(g1 + (size_t)(n0 + r) * NDIM);
  const float4* q2 = (const float4*)(g2 + (size_t)(n0 + r) * NDIM);
#pragma unroll
  for (int i = 0; i < 4; ++i) {
    int q = (tid & 3) + i * 4;
    float4 a = ok ? hp[q] : float4{0.f, 0.f, 0.f, 0.f};
    float4 b = ok ? q1[q] : float4{0.f, 0.f, 0.f, 0.f};
    float4 c = ok ? q2[q] : float4{0.f, 0.f, 0.f, 0.f};
    Ht[r][q*4+0]=a.x;  Ht[r][q*4+1]=a.y;  Ht[r][q*4+2]=a.z;  Ht[r][q*4+3]=a.w;
    G1t[r][q*4+0]=b.x; G1t[r][q*4+1]=b.y; G1t[r][q*4+2]=b.z; G1t[r][q*4+3]=b.w;
    G2t[r][q*4+0]=c.x; G2t[r][q*4+1]=c.y; G2t[r][q*4+2]=c.z; G2t[r][q*4+3]=c.w;
  }
  __syncthreads();
  int w = __builtin_amdgcn_readfirstlane(tid >> 6);
  int lane = tid & 63;
  int ob = w * 16;
  float acc[16];
#pragma unroll
  for (int o = 0; o < 16; ++o) acc[o] = bias[ob + o];
  float4 nA[4], nB[4], nC[4];
  float nh, n1v, n2v;
  {
    const float4* pa = (const float4*)(wrT + ob);
    const float4* pb = (const float4*)(w1T + ob);
    const float4* pc = (const float4*)(w2T + ob);
#pragma unroll
    for (int j = 0; j < 4; ++j) { nA[j] = pa[j]; nB[j] = pb[j]; nC[j] = pc[j]; }
    nh = Ht[lane][0]; n1v = G1t[lane][0]; n2v = G2t[lane][0];
  }
  for (int k = 0; k < 64; ++k) {
    float4 A[4], B[4], C[4];
    float hv = nh, v1 = n1v, v2 = n2v;
#pragma unroll
    for (int j = 0; j < 4; ++j) { A[j] = nA[j]; B[j] = nB[j]; C[j] = nC[j]; }
    if (k < 63) {
      int k1 = k + 1;
      const float4* pa = (const float4*)(wrT + k1 * 64 + ob);
      const float4* pb = (const float4*)(w1T + k1 * 64 + ob);
      const float4* pc = (const float4*)(w2T + k1 * 64 + ob);
#pragma unroll
      for (int j = 0; j < 4; ++j) { nA[j] = pa[j]; nB[j] = pb[j]; nC[j] = pc[j]; }
      nh = Ht[lane][k1]; n1v = G1t[lane][k1]; n2v = G2t[lane][k1];
    }
#pragma unroll
    for (int j = 0; j < 4; ++j) {
      acc[4*j+0] += hv * A[j].x + v1 * B[j].x + v2 * C[j].x;
      acc[4*j+1] += hv * A[j].y + v1 * B[j].y + v2 * C[j].y;
      acc[4*j+2] += hv * A[j].z + v1 * B[j].z + v2 * C[j].z;
      acc[4*j+3] += hv * A[j].w + v1 * B[j].w + v2 * C[j].w;
    }
  }
  int node = n0 + lane;
  if (node < N) {
    float rl[16];
#pragma unroll
    for (int o = 0; o < 16; ++o) rl[o] = fmaxf(acc[o], 0.f);
    float4* op = (float4*)(hout + (size_t)node * NDIM + ob);
#pragma unroll
    for (int j = 0; j < 4; ++j) {
      float4 v;
      v.x = rl[4*j+0]; v.y = rl[4*j+1]; v.z = rl[4*j+2]; v.w = rl[4*j+3];
      op[j] = v;
    }
    if (hbout) {
      uint4 u0, u1;
      u0.x = f2bf2(rl[0],  rl[1]);  u0.y = f2bf2(rl[2],  rl[3]);
      u0.z = f2bf2(rl[4],  rl[5]);  u0.w = f2bf2(rl[6],  rl[7]);
      u1.x = f2bf2(rl[8],  rl[9]);  u1.y = f2bf2(rl[10], rl[11]);
      u1.z = f2bf2(rl[12], rl[13]); u1.w = f2bf2(rl[14], rl[15]);
      uint4* bp = (uint4*)(hbout + (size_t)node * NDIM + ob);
      bp[0] = u0; bp[1] = u1;
    }
  }
}

// ---------------- final: 64-node LDS tile (4 input bufs), lane=node ----------------

__global__ __launch_bounds__(256, 2) void final_kernel(
    const float* __restrict__ x, const float* __restrict__ h1,
    const float* __restrict__ h2, const float* __restrict__ h3,
    const float* __restrict__ fwT, const float* __restrict__ fb,
    float* __restrict__ outp, int N) {
  __shared__ float Ft[4][64][65];
  int tid = threadIdx.x;
  int n0 = blockIdx.x * 64;
  int r = tid >> 2;
  bool ok = (n0 + r) < N;
  const float* bufs[4] = {x, h1, h2, h3};
#pragma unroll
  for (int b = 0; b < 4; ++b) {
    const float4* ip = (const float4*)(bufs[b] + (size_t)(n0 + r) * NDIM);
#pragma unroll
    for (int i = 0; i < 4; ++i) {
      int q = (tid & 3) + i * 4;
      float4 v = ok ? ip[q] : float4{0.f, 0.f, 0.f, 0.f};
      Ft[b][r][q*4+0]=v.x; Ft[b][r][q*4+1]=v.y; Ft[b][r][q*4+2]=v.z; Ft[b][r][q*4+3]=v.w;
    }
  }
  __syncthreads();
  int w = __builtin_amdgcn_readfirstlane(tid >> 6);
  int lane = tid & 63;
  int ob = w * 16;
  float acc[16];
#pragma unroll
  for (int o = 0; o < 16; ++o) acc[o] = fb[ob + o];
  float4 nW[4];
  float nv;
  {
    const float4* wp = (const float4*)(fwT + ob);
#pragma unroll
    for (int j = 0; j < 4; ++j) nW[j] = wp[j];
    nv = Ft[0][lane][0];
  }
  for (int k = 0; k < 256; ++k) {
    float4 W[4];
    float v = nv;
#pragma unroll
    for (int j = 0; j < 4; ++j) W[j] = nW[j];
    if (k < 255) {
      int k1 = k + 1;
      const float4* wp = (const float4*)(fwT + k1 * 64 + ob);
#pragma unroll
      for (int j = 0; j < 4; ++j) nW[j] = wp[j];
      nv = Ft[k1 >> 6][lane][k1 & 63];
    }
#pragma unroll
    for (int j = 0; j < 4; ++j) {
      acc[4*j+0] += v * W[j].x;
      acc[4*j+1] += v * W[j].y;
      acc[4*j+2] += v * W[j].z;
      acc[4*j+3] += v * W[j].w;
    }
  }
  int node = n0 + lane;
  if (node < N) {
    float4* op = (float4*)(outp + (size_t)node * NDIM + ob);
#pragma unroll
    for (int j = 0; j < 4; ++j) {
      float4 v;
      v.x = acc[4*j+0]; v.y = acc[4*j+1]; v.z = acc[4*j+2]; v.w = acc[4*j+3];
      op[j] = v;
    }
  }
}

// ---------------- launch ----------------

extern "C" void kernel_launch(void* const* d_in, const int* in_sizes, int n_in,
                              void* d_out, int out_size, void* d_ws, size_t ws_size,
                              hipStream_t stream) {
  const float* x     = (const float*)d_in[0];
  const int*   ei    = (const int*)d_in[1];
  const float* lin1  = (const float*)d_in[2];
  const float* lin2  = (const float*)d_in[3];
  const float* rootw = (const float*)d_in[4];
  const float* rootb = (const float*)d_in[5];
  const float* fw    = (const float*)d_in[6];
  const float* fb    = (const float*)d_in[7];
  float* out = (float*)d_out;

  int N = in_sizes[0] / NDIM;
  int E = in_sizes[1] / 2;
  const int* src = ei;
  const int* dst = ei + E;

  int* ip = (int*)d_ws;
  int* Hd    = ip; ip += (size_t)NCHK * N;
  int* Hs    = ip; ip += (size_t)NCHK * N;
  int* deg_d = ip; ip += N;
  int* deg_s = ip; ip += N;
  int* row_d = ip; ip += N + 1;
  int* row_s = ip; ip += N + 1;
  int* bsum  = ip; ip += 256;
  int* col_d = ip; ip += E;
  int* col_s = ip; ip += E;
  uintptr_t fbase = (((uintptr_t)ip) + 255) & ~(uintptr_t)255;
  float* fwT = (float*)fbase;
  float* wrT = fwT + 16384;
  float* w1T = wrT + 12288;
  float* w2T = w1T + 12288;
  float* h1  = w2T + 12288;
  float* h2 = h1 + (size_t)N * NDIM;
  float* h3 = h2 + (size_t)N * NDIM;
  float* g1 = h3 + (size_t)N * NDIM;
  float* g2 = g1 + (size_t)N * NDIM;
  ushort* hB0 = (ushort*)(g2 + (size_t)N * NDIM);
  ushort* hB1 = hB0 + (size_t)N * NDIM;
  ushort* hB2 = hB1 + (size_t)N * NDIM;

  int chunk = (E + NCHK - 1) / NCHK;
  int nb = (N + SCAN_ELEMS - 1) / SCAN_ELEMS;
  int nblk = (N + 255) / 256;

  transpose_kernel<<<112, 256, 0, stream>>>(fw, rootw, lin1, lin2, fwT, wrT, w1T, w2T);
  convx_kernel<<<(N * 16 + 255) / 256, 256, 0, stream>>>(x, (uint*)hB0, N * 16);
  hist_kernel<<<dim3(NCHK, NGRP), 256, 0, stream>>>(src, dst, Hd, Hs, E, N, chunk);
  degsum_kernel<<<nblk, 256, 0, stream>>>(Hd, Hs, deg_d, deg_s, N);
  scan_partial<<<dim3(nb, 2), 256, 0, stream>>>(deg_d, deg_s, bsum, N, nb);
  scan_bsum<<<1, 256, 0, stream>>>(bsum, nb);
  scan_final<<<dim3(nb, 2), 256, 0, stream>>>(deg_d, deg_s, bsum, row_d, row_s, N, nb);
  cursor_kernel<<<nblk, 256, 0, stream>>>(Hd, Hs, row_d, row_s, N);
  scatter_kernel<<<dim3(NGRP, NCHK), 256, 0, stream>>>(src, dst, Hd, Hs,
                                                       col_d, col_s, E, N, chunk);

  int ab = (N + 3) / 4;
  int tgrid = (N + 63) / 64;
  const float*  hbufs[4]  = {x, h1, h2, h3};
  const ushort* hBbufs[3] = {hB0, hB1, hB2};
  for (int l = 0; l < 3; ++l) {
    agg4_kernel<<<dim3(ab, 4), 256, 0, stream>>>(hBbufs[l], row_d, col_d, g1,
                                                 row_s, col_s, g2, N);
    ushort* hbnext = (l < 2) ? (ushort*)hBbufs[l + 1] : (ushort*)nullptr;
    combine_kernel<<<tgrid, 256, 0, stream>>>(hbufs[l], g1, g2,
                                              wrT + (size_t)l * 4096,
                                              w1T + (size_t)l * 4096,
                                              w2T + (size_t)l * 4096,
                                              rootb + (size_t)l * 64,
                                              (float*)hbufs[l + 1], hbnext, N);
  }
  final_kernel<<<tgrid, 256, 0, stream>>>(x, h1, h2, h3, fwT, fb, out, N);
}

// Round 10
// 409.482 us; speedup vs baseline: 1.2734x; 1.2734x over previous
//
#include <hip/hip_runtime.h>
#include <stdint.h>

#define NDIM 64
#define SCAN_ELEMS 2048   // elements per scan block (256 thr x 8)
#define NCHK 16           // edge chunks
#define NGRP 8            // node-range groups
#define RMAX 6272         // max nodes per group (ceil(50000/8)=6250)

typedef unsigned int uint;
typedef unsigned short ushort;

// round-to-nearest-even fp32 -> bf16 (pair packed into a uint)
__device__ __forceinline__ uint f2bf2(float a, float b) {
  uint ua = __float_as_uint(a);
  uint ub = __float_as_uint(b);
  ua += 0x7fffu + ((ua >> 16) & 1u);
  ub += 0x7fffu + ((ub >> 16) & 1u);
  return (ua >> 16) | (ub & 0xffff0000u);
}

// ---------------- weight transpose (k-major) ----------------
__global__ __launch_bounds__(256) void transpose_kernel(
    const float* __restrict__ fw, const float* __restrict__ rootw,
    const float* __restrict__ lin1, const float* __restrict__ lin2,
    float* __restrict__ fwT, float* __restrict__ wrT,
    float* __restrict__ w1T, float* __restrict__ w2T) {
  int e = blockIdx.x * 256 + threadIdx.x;
  if (e < 16384) {
    int o = e >> 8, k = e & 255;
    fwT[k * 64 + o] = fw[e];
  }
  int e2 = e - 16384;
  if (e2 >= 0 && e2 < 12288) {
    int l = e2 >> 12, r = e2 & 4095;
    int o = r >> 6, k = r & 63;
    size_t t = (size_t)l * 4096 + k * 64 + o;
    wrT[t] = rootw[e2];
    w1T[t] = lin1[e2];
    w2T[t] = lin2[e2];
  }
}

// ---------------- x -> bf16 table ----------------
__global__ __launch_bounds__(256) void convx_kernel(
    const float* __restrict__ x, uint* __restrict__ xb, int n4) {
  int e = blockIdx.x * 256 + threadIdx.x;
  if (e >= n4) return;
  float4 v = ((const float4*)x)[e];
  uint2 o;
  o.x = f2bf2(v.x, v.y);
  o.y = f2bf2(v.z, v.w);
  ((uint2*)xb)[e] = o;
}

// ---------------- CSR build: atomic-free chunked counting sort ----------------
__global__ __launch_bounds__(256) void hist_kernel(
    const int* __restrict__ src, const int* __restrict__ dst,
    int* __restrict__ Hd, int* __restrict__ Hs, int E, int N, int chunk) {
  int c = blockIdx.x, g = blockIdx.y;
  int lo = (int)((long long)N * g / NGRP);
  int hi = (int)((long long)N * (g + 1) / NGRP);
  int range = hi - lo;
  __shared__ int cntd[RMAX];
  __shared__ int cnts[RMAX];
  for (int i = threadIdx.x; i < range; i += 256) { cntd[i] = 0; cnts[i] = 0; }
  __syncthreads();
  int e0 = c * chunk, e1 = min(E, e0 + chunk);
  for (int e = e0 + (int)threadIdx.x * 4; e < e1; e += 1024) {
    if (e + 4 <= e1) {
      int4 s4 = *(const int4*)(src + e);
      int4 d4 = *(const int4*)(dst + e);
      if (d4.x >= lo && d4.x < hi) atomicAdd(&cntd[d4.x - lo], 1);
      if (d4.y >= lo && d4.y < hi) atomicAdd(&cntd[d4.y - lo], 1);
      if (d4.z >= lo && d4.z < hi) atomicAdd(&cntd[d4.z - lo], 1);
      if (d4.w >= lo && d4.w < hi) atomicAdd(&cntd[d4.w - lo], 1);
      if (s4.x >= lo && s4.x < hi) atomicAdd(&cnts[s4.x - lo], 1);
      if (s4.y >= lo && s4.y < hi) atomicAdd(&cnts[s4.y - lo], 1);
      if (s4.z >= lo && s4.z < hi) atomicAdd(&cnts[s4.z - lo], 1);
      if (s4.w >= lo && s4.w < hi) atomicAdd(&cnts[s4.w - lo], 1);
    } else {
      for (int k = e; k < e1; ++k) {
        int s = src[k], d = dst[k];
        if (d >= lo && d < hi) atomicAdd(&cntd[d - lo], 1);
        if (s >= lo && s < hi) atomicAdd(&cnts[s - lo], 1);
      }
    }
  }
  __syncthreads();
  for (int i = threadIdx.x; i < range; i += 256) {
    Hd[(size_t)c * N + lo + i] = cntd[i];
    Hs[(size_t)c * N + lo + i] = cnts[i];
  }
}

__global__ __launch_bounds__(256) void degsum_kernel(
    const int* __restrict__ Hd, const int* __restrict__ Hs,
    int* __restrict__ deg_d, int* __restrict__ deg_s, int N) {
  int n = blockIdx.x * 256 + threadIdx.x;
  if (n >= N) return;
  int sd = 0, ss = 0;
#pragma unroll
  for (int c = 0; c < NCHK; ++c) {
    sd += Hd[(size_t)c * N + n];
    ss += Hs[(size_t)c * N + n];
  }
  deg_d[n] = sd;
  deg_s[n] = ss;
}

__global__ __launch_bounds__(256) void scan_partial(
    const int* __restrict__ deg_d, const int* __restrict__ deg_s,
    int* __restrict__ bsum, int n, int nb) {
  const int* deg = (blockIdx.y == 0) ? deg_d : deg_s;
  int tid = threadIdx.x;
  int base = blockIdx.x * SCAN_ELEMS;
  int s = 0;
#pragma unroll
  for (int j = 0; j < 8; ++j) {
    int i = base + j * 256 + tid;
    if (i < n) s += deg[i];
  }
#pragma unroll
  for (int off = 1; off < 64; off <<= 1) s += __shfl_xor(s, off);
  __shared__ int ws[4];
  if ((tid & 63) == 0) ws[tid >> 6] = s;
  __syncthreads();
  if (tid == 0) bsum[blockIdx.y * nb + blockIdx.x] = ws[0] + ws[1] + ws[2] + ws[3];
}

__global__ __launch_bounds__(256) void scan_bsum(int* __restrict__ bsum, int nb) {
  __shared__ int sh[256];
  int tid = threadIdx.x;
  for (int h = 0; h < 2; ++h) {
    int v = (tid < nb) ? bsum[h * nb + tid] : 0;
    sh[tid] = v;
    __syncthreads();
    for (int off = 1; off < 256; off <<= 1) {
      int t = (tid >= off) ? sh[tid - off] : 0;
      __syncthreads();
      sh[tid] += t;
      __syncthreads();
    }
    if (tid < nb) bsum[h * nb + tid] = sh[tid] - v;  // exclusive
    __syncthreads();
  }
}

__global__ __launch_bounds__(256) void scan_final(
    const int* __restrict__ deg_d, const int* __restrict__ deg_s,
    const int* __restrict__ bsum,
    int* __restrict__ row_d, int* __restrict__ row_s, int n, int nb) {
  const int* deg = (blockIdx.y == 0) ? deg_d : deg_s;
  int* row = (blockIdx.y == 0) ? row_d : row_s;
  int tid = threadIdx.x;
  int lane = tid & 63;
  int e0 = blockIdx.x * SCAN_ELEMS + tid * 8;
  int v[8];
  int s = 0;
#pragma unroll
  for (int j = 0; j < 8; ++j) {
    int i = e0 + j;
    v[j] = (i < n) ? deg[i] : 0;
    s += v[j];
  }
  int incl = s;
#pragma unroll
  for (int off = 1; off < 64; off <<= 1) {
    int t = __shfl_up(incl, off);
    if (lane >= off) incl += t;
  }
  __shared__ int wsum[4];
  if (lane == 63) wsum[tid >> 6] = incl;
  __syncthreads();
  int woff = 0;
  int w = tid >> 6;
  for (int k = 0; k < 4; ++k)
    if (k < w) woff += wsum[k];
  int run = incl - s + woff + bsum[blockIdx.y * nb + blockIdx.x];
#pragma unroll
  for (int j = 0; j < 8; ++j) {
    int i = e0 + j;
    if (i <= n) row[i] = run;
    run += v[j];
  }
}

__global__ __launch_bounds__(256) void cursor_kernel(
    int* __restrict__ Hd, int* __restrict__ Hs,
    const int* __restrict__ row_d, const int* __restrict__ row_s, int N) {
  int n = blockIdx.x * 256 + threadIdx.x;
  if (n >= N) return;
  int rd = row_d[n], rs = row_s[n];
#pragma unroll
  for (int c = 0; c < NCHK; ++c) {
    int t = Hd[(size_t)c * N + n]; Hd[(size_t)c * N + n] = rd; rd += t;
    t = Hs[(size_t)c * N + n];     Hs[(size_t)c * N + n] = rs; rs += t;
  }
}

// scatter: grid (x=g, y=c) so linear_id%8 == g -> each col region has a
// single-writer XCD (kills write-line ping-pong). Edge chunks stay L3-hot.
__global__ __launch_bounds__(256) void scatter_kernel(
    const int* __restrict__ src, const int* __restrict__ dst,
    const int* __restrict__ Hd, const int* __restrict__ Hs,
    int* __restrict__ col_d, int* __restrict__ col_s, int E, int N, int chunk) {
  int g = blockIdx.x, c = blockIdx.y;
  int lo = (int)((long long)N * g / NGRP);
  int hi = (int)((long long)N * (g + 1) / NGRP);
  int range = hi - lo;
  __shared__ int curd[RMAX];
  __shared__ int curs[RMAX];
  for (int i = threadIdx.x; i < range; i += 256) {
    curd[i] = Hd[(size_t)c * N + lo + i];
    curs[i] = Hs[(size_t)c * N + lo + i];
  }
  __syncthreads();
  int e0 = c * chunk, e1 = min(E, e0 + chunk);
  for (int e = e0 + (int)threadIdx.x * 4; e < e1; e += 1024) {
    if (e + 4 <= e1) {
      int4 s4 = *(const int4*)(src + e);
      int4 d4 = *(const int4*)(dst + e);
      if (d4.x >= lo && d4.x < hi) { int p = atomicAdd(&curd[d4.x - lo], 1); col_d[p] = s4.x; }
      if (d4.y >= lo && d4.y < hi) { int p = atomicAdd(&curd[d4.y - lo], 1); col_d[p] = s4.y; }
      if (d4.z >= lo && d4.z < hi) { int p = atomicAdd(&curd[d4.z - lo], 1); col_d[p] = s4.z; }
      if (d4.w >= lo && d4.w < hi) { int p = atomicAdd(&curd[d4.w - lo], 1); col_d[p] = s4.w; }
      if (s4.x >= lo && s4.x < hi) { int p = atomicAdd(&curs[s4.x - lo], 1); col_s[p] = d4.x; }
      if (s4.y >= lo && s4.y < hi) { int p = atomicAdd(&curs[s4.y - lo], 1); col_s[p] = d4.y; }
      if (s4.z >= lo && s4.z < hi) { int p = atomicAdd(&curs[s4.z - lo], 1); col_s[p] = d4.z; }
      if (s4.w >= lo && s4.w < hi) { int p = atomicAdd(&curs[s4.w - lo], 1); col_s[p] = d4.w; }
    } else {
      for (int k = e; k < e1; ++k) {
        int s = src[k], d = dst[k];
        if (d >= lo && d < hi) { int p = atomicAdd(&curd[d - lo], 1); col_d[p] = s; }
        if (s >= lo && s < hi) { int p = atomicAdd(&curs[s - lo], 1); col_s[p] = d; }
      }
    }
  }
}

// ---------------- aggregation (bf16, 8 neighbors per load instruction) ----------------
// Lane g=lane>>3 owns neighbor slot g, fl=lane&7 owns features [fl*8,fl*8+8).
// One global_load_dwordx4 per wave fetches 8 full bf16 rows (16B/lane).
// Cross-slot reduce: shfl_xor 8/16/32; lanes g==0 store the fp32 mean row.

#define UNPACK_ACC(A, U) {                                                   \
    A[0] += __uint_as_float((U).x << 16);                                    \
    A[1] += __uint_as_float((U).x & 0xffff0000u);                            \
    A[2] += __uint_as_float((U).y << 16);                                    \
    A[3] += __uint_as_float((U).y & 0xffff0000u);                            \
    A[4] += __uint_as_float((U).z << 16);                                    \
    A[5] += __uint_as_float((U).z & 0xffff0000u);                            \
    A[6] += __uint_as_float((U).w << 16);                                    \
    A[7] += __uint_as_float((U).w & 0xffff0000u); }

__global__ __launch_bounds__(256) void agg8_kernel(
    const ushort* __restrict__ hB,
    const int* __restrict__ row_d, const int* __restrict__ col_d, float* __restrict__ g1,
    const int* __restrict__ row_s, const int* __restrict__ col_s, float* __restrict__ g2,
    int N) {
  const int* row = (blockIdx.y == 0) ? row_d : row_s;
  const int* col = (blockIdx.y == 0) ? col_d : col_s;
  float* outp = (blockIdx.y == 0) ? g1 : g2;
  int wid = blockIdx.x * 4 + (threadIdx.x >> 6);
  int lane = threadIdx.x & 63;
  int g = lane >> 3;
  int fl = lane & 7;
  if (wid >= N) return;
  int s0 = row[wid], s1 = row[wid + 1];
  const ushort* tab = hB + fl * 8;
  float a[8] = {0.f, 0.f, 0.f, 0.f, 0.f, 0.f, 0.f, 0.f};
  float b[8] = {0.f, 0.f, 0.f, 0.f, 0.f, 0.f, 0.f, 0.f};
  int p = s0;
  for (; p + 16 <= s1; p += 16) {
    int n0 = col[p + g];
    int n1 = col[p + 8 + g];
    uint4 u0 = *(const uint4*)(tab + (size_t)n0 * 64);
    uint4 u1 = *(const uint4*)(tab + (size_t)n1 * 64);
    UNPACK_ACC(a, u0);
    UNPACK_ACC(b, u1);
  }
  if (p + 8 <= s1) {
    int n = col[p + g];
    uint4 u = *(const uint4*)(tab + (size_t)n * 64);
    UNPACK_ACC(a, u);
    p += 8;
  }
  if (p + g < s1) {
    int n = col[p + g];
    uint4 u = *(const uint4*)(tab + (size_t)n * 64);
    UNPACK_ACC(b, u);
  }
#pragma unroll
  for (int i = 0; i < 8; ++i) a[i] += b[i];
#pragma unroll
  for (int i = 0; i < 8; ++i) {
    a[i] += __shfl_xor(a[i], 8);
    a[i] += __shfl_xor(a[i], 16);
    a[i] += __shfl_xor(a[i], 32);
  }
  int cnt = s1 - s0;
  float inv = cnt > 0 ? 1.f / (float)cnt : 0.f;
  if (g == 0) {
    float4 v0; v0.x = a[0]*inv; v0.y = a[1]*inv; v0.z = a[2]*inv; v0.w = a[3]*inv;
    float4 v1; v1.x = a[4]*inv; v1.y = a[5]*inv; v1.z = a[6]*inv; v1.w = a[7]*inv;
    float4* op = (float4*)(outp + (size_t)wid * NDIM + fl * 8);
    op[0] = v0;
    op[1] = v1;
  }
}

// ---------------- combine: 64-node LDS tile, lane=node, wave=16 outputs ----------------

__global__ __launch_bounds__(256, 3) void combine_kernel(
    const float* __restrict__ h, const float* __restrict__ g1,
    const float* __restrict__ g2, const float* __restrict__ wrT,
    const float* __restrict__ w1T, const float* __restrict__ w2T,
    const float* __restrict__ bias, float* __restrict__ hout,
    ushort* __restrict__ hbout, int N) {
  __shared__ float Ht[64][65];
  __shared__ float G1t[64][65];
  __shared__ float G2t[64][65];
  int tid = threadIdx.x;
  int n0 = blockIdx.x * 64;
  int r = tid >> 2;
  bool ok = (n0 + r) < N;
  const float4* hp = (const float4*)(h  + (size_t)(n0 + r) * NDIM);
  const float4* q1 = (const float4*)(g1 + (size_t)(n0 + r) * NDIM);
  const float4* q2 = (const float4*)(g2 + (size_t)(n0 + r) * NDIM);
#pragma unroll
  for (int i = 0; i < 4; ++i) {
    int q = (tid & 3) + i * 4;
    float4 a = ok ? hp[q] : float4{0.f, 0.f, 0.f, 0.f};
    float4 b = ok ? q1[q] : float4{0.f, 0.f, 0.f, 0.f};
    float4 c = ok ? q2[q] : float4{0.f, 0.f, 0.f, 0.f};
    Ht[r][q*4+0]=a.x;  Ht[r][q*4+1]=a.y;  Ht[r][q*4+2]=a.z;  Ht[r][q*4+3]=a.w;
    G1t[r][q*4+0]=b.x; G1t[r][q*4+1]=b.y; G1t[r][q*4+2]=b.z; G1t[r][q*4+3]=b.w;
    G2t[r][q*4+0]=c.x; G2t[r][q*4+1]=c.y; G2t[r][q*4+2]=c.z; G2t[r][q*4+3]=c.w;
  }
  __syncthreads();
  int w = __builtin_amdgcn_readfirstlane(tid >> 6);
  int lane = tid & 63;
  int ob = w * 16;
  float acc[16];
#pragma unroll
  for (int o = 0; o < 16; ++o) acc[o] = bias[ob + o];
  float4 nA[4], nB[4], nC[4];
  float nh, n1v, n2v;
  {
    const float4* pa = (const float4*)(wrT + ob);
    const float4* pb = (const float4*)(w1T + ob);
    const float4* pc = (const float4*)(w2T + ob);
#pragma unroll
    for (int j = 0; j < 4; ++j) { nA[j] = pa[j]; nB[j] = pb[j]; nC[j] = pc[j]; }
    nh = Ht[lane][0]; n1v = G1t[lane][0]; n2v = G2t[lane][0];
  }
  for (int k = 0; k < 64; ++k) {
    float4 A[4], B[4], C[4];
    float hv = nh, v1 = n1v, v2 = n2v;
#pragma unroll
    for (int j = 0; j < 4; ++j) { A[j] = nA[j]; B[j] = nB[j]; C[j] = nC[j]; }
    if (k < 63) {
      int k1 = k + 1;
      const float4* pa = (const float4*)(wrT + k1 * 64 + ob);
      const float4* pb = (const float4*)(w1T + k1 * 64 + ob);
      const float4* pc = (const float4*)(w2T + k1 * 64 + ob);
#pragma unroll
      for (int j = 0; j < 4; ++j) { nA[j] = pa[j]; nB[j] = pb[j]; nC[j] = pc[j]; }
      nh = Ht[lane][k1]; n1v = G1t[lane][k1]; n2v = G2t[lane][k1];
    }
#pragma unroll
    for (int j = 0; j < 4; ++j) {
      acc[4*j+0] += hv * A[j].x + v1 * B[j].x + v2 * C[j].x;
      acc[4*j+1] += hv * A[j].y + v1 * B[j].y + v2 * C[j].y;
      acc[4*j+2] += hv * A[j].z + v1 * B[j].z + v2 * C[j].z;
      acc[4*j+3] += hv * A[j].w + v1 * B[j].w + v2 * C[j].w;
    }
  }
  int node = n0 + lane;
  if (node < N) {
    float rl[16];
#pragma unroll
    for (int o = 0; o < 16; ++o) rl[o] = fmaxf(acc[o], 0.f);
    float4* op = (float4*)(hout + (size_t)node * NDIM + ob);
#pragma unroll
    for (int j = 0; j < 4; ++j) {
      float4 v;
      v.x = rl[4*j+0]; v.y = rl[4*j+1]; v.z = rl[4*j+2]; v.w = rl[4*j+3];
      op[j] = v;
    }
    if (hbout) {
      uint4 u0, u1;
      u0.x = f2bf2(rl[0],  rl[1]);  u0.y = f2bf2(rl[2],  rl[3]);
      u0.z = f2bf2(rl[4],  rl[5]);  u0.w = f2bf2(rl[6],  rl[7]);
      u1.x = f2bf2(rl[8],  rl[9]);  u1.y = f2bf2(rl[10], rl[11]);
      u1.z = f2bf2(rl[12], rl[13]); u1.w = f2bf2(rl[14], rl[15]);
      uint4* bp = (uint4*)(hbout + (size_t)node * NDIM + ob);
      bp[0] = u0; bp[1] = u1;
    }
  }
}

// ---------------- final: 64-node LDS tile (4 input bufs), lane=node ----------------

__global__ __launch_bounds__(256, 2) void final_kernel(
    const float* __restrict__ x, const float* __restrict__ h1,
    const float* __restrict__ h2, const float* __restrict__ h3,
    const float* __restrict__ fwT, const float* __restrict__ fb,
    float* __restrict__ outp, int N) {
  __shared__ float Ft[4][64][65];
  int tid = threadIdx.x;
  int n0 = blockIdx.x * 64;
  int r = tid >> 2;
  bool ok = (n0 + r) < N;
  const float* bufs[4] = {x, h1, h2, h3};
#pragma unroll
  for (int b = 0; b < 4; ++b) {
    const float4* ip = (const float4*)(bufs[b] + (size_t)(n0 + r) * NDIM);
#pragma unroll
    for (int i = 0; i < 4; ++i) {
      int q = (tid & 3) + i * 4;
      float4 v = ok ? ip[q] : float4{0.f, 0.f, 0.f, 0.f};
      Ft[b][r][q*4+0]=v.x; Ft[b][r][q*4+1]=v.y; Ft[b][r][q*4+2]=v.z; Ft[b][r][q*4+3]=v.w;
    }
  }
  __syncthreads();
  int w = __builtin_amdgcn_readfirstlane(tid >> 6);
  int lane = tid & 63;
  int ob = w * 16;
  float acc[16];
#pragma unroll
  for (int o = 0; o < 16; ++o) acc[o] = fb[ob + o];
  float4 nW[4];
  float nv;
  {
    const float4* wp = (const float4*)(fwT + ob);
#pragma unroll
    for (int j = 0; j < 4; ++j) nW[j] = wp[j];
    nv = Ft[0][lane][0];
  }
  for (int k = 0; k < 256; ++k) {
    float4 W[4];
    float v = nv;
#pragma unroll
    for (int j = 0; j < 4; ++j) W[j] = nW[j];
    if (k < 255) {
      int k1 = k + 1;
      const float4* wp = (const float4*)(fwT + k1 * 64 + ob);
#pragma unroll
      for (int j = 0; j < 4; ++j) nW[j] = wp[j];
      nv = Ft[k1 >> 6][lane][k1 & 63];
    }
#pragma unroll
    for (int j = 0; j < 4; ++j) {
      acc[4*j+0] += v * W[j].x;
      acc[4*j+1] += v * W[j].y;
      acc[4*j+2] += v * W[j].z;
      acc[4*j+3] += v * W[j].w;
    }
  }
  int node = n0 + lane;
  if (node < N) {
    float4* op = (float4*)(outp + (size_t)node * NDIM + ob);
#pragma unroll
    for (int j = 0; j < 4; ++j) {
      float4 v;
      v.x = acc[4*j+0]; v.y = acc[4*j+1]; v.z = acc[4*j+2]; v.w = acc[4*j+3];
      op[j] = v;
    }
  }
}

// ---------------- launch ----------------

extern "C" void kernel_launch(void* const* d_in, const int* in_sizes, int n_in,
                              void* d_out, int out_size, void* d_ws, size_t ws_size,
                              hipStream_t stream) {
  const float* x     = (const float*)d_in[0];
  const int*   ei    = (const int*)d_in[1];
  const float* lin1  = (const float*)d_in[2];
  const float* lin2  = (const float*)d_in[3];
  const float* rootw = (const float*)d_in[4];
  const float* rootb = (const float*)d_in[5];
  const float* fw    = (const float*)d_in[6];
  const float* fb    = (const float*)d_in[7];
  float* out = (float*)d_out;

  int N = in_sizes[0] / NDIM;
  int E = in_sizes[1] / 2;
  const int* src = ei;
  const int* dst = ei + E;

  int* ip = (int*)d_ws;
  int* Hd    = ip; ip += (size_t)NCHK * N;
  int* Hs    = ip; ip += (size_t)NCHK * N;
  int* deg_d = ip; ip += N;
  int* deg_s = ip; ip += N;
  int* row_d = ip; ip += N + 1;
  int* row_s = ip; ip += N + 1;
  int* bsum  = ip; ip += 256;
  int* col_d = ip; ip += E;
  int* col_s = ip; ip += E;
  uintptr_t fbase = (((uintptr_t)ip) + 255) & ~(uintptr_t)255;
  float* fwT = (float*)fbase;
  float* wrT = fwT + 16384;
  float* w1T = wrT + 12288;
  float* w2T = w1T + 12288;
  float* h1  = w2T + 12288;
  float* h2 = h1 + (size_t)N * NDIM;
  float* h3 = h2 + (size_t)N * NDIM;
  float* g1 = h3 + (size_t)N * NDIM;
  float* g2 = g1 + (size_t)N * NDIM;
  ushort* hB0 = (ushort*)(g2 + (size_t)N * NDIM);
  ushort* hB1 = hB0 + (size_t)N * NDIM;
  ushort* hB2 = hB1 + (size_t)N * NDIM;

  int chunk = (E + NCHK - 1) / NCHK;
  int nb = (N + SCAN_ELEMS - 1) / SCAN_ELEMS;
  int nblk = (N + 255) / 256;

  transpose_kernel<<<112, 256, 0, stream>>>(fw, rootw, lin1, lin2, fwT, wrT, w1T, w2T);
  convx_kernel<<<(N * 16 + 255) / 256, 256, 0, stream>>>(x, (uint*)hB0, N * 16);
  hist_kernel<<<dim3(NCHK, NGRP), 256, 0, stream>>>(src, dst, Hd, Hs, E, N, chunk);
  degsum_kernel<<<nblk, 256, 0, stream>>>(Hd, Hs, deg_d, deg_s, N);
  scan_partial<<<dim3(nb, 2), 256, 0, stream>>>(deg_d, deg_s, bsum, N, nb);
  scan_bsum<<<1, 256, 0, stream>>>(bsum, nb);
  scan_final<<<dim3(nb, 2), 256, 0, stream>>>(deg_d, deg_s, bsum, row_d, row_s, N, nb);
  cursor_kernel<<<nblk, 256, 0, stream>>>(Hd, Hs, row_d, row_s, N);
  scatter_kernel<<<dim3(NGRP, NCHK), 256, 0, stream>>>(src, dst, Hd, Hs,
                                                       col_d, col_s, E, N, chunk);

  int ab = (N + 3) / 4;
  int tgrid = (N + 63) / 64;
  const float*  hbufs[4]  = {x, h1, h2, h3};
  const ushort* hBbufs[3] = {hB0, hB1, hB2};
  for (int l = 0; l < 3; ++l) {
    agg8_kernel<<<dim3(ab, 2), 256, 0, stream>>>(hBbufs[l], row_d, col_d, g1,
                                                 row_s, col_s, g2, N);
    ushort* hbnext = (l < 2) ? (ushort*)hBbufs[l + 1] : (ushort*)nullptr;
    combine_kernel<<<tgrid, 256, 0, stream>>>(hbufs[l], g1, g2,
                                              wrT + (size_t)l * 4096,
                                              w1T + (size_t)l * 4096,
                                              w2T + (size_t)l * 4096,
                                              rootb + (size_t)l * 64,
                                              (float*)hbufs[l + 1], hbnext, N);
  }
  final_kernel<<<tgrid, 256, 0, stream>>>(x, h1, h2, h3, fwT, fb, out, N);
}

// Round 11
// 370.626 us; speedup vs baseline: 1.4069x; 1.1048x over previous
//
#include <hip/hip_runtime.h>
#include <stdint.h>

#define NDIM 64
#define SCAN_ELEMS 2048   // elements per scan block (256 thr x 8)
#define NCHK 32           // edge chunks
#define NGRP 8            // node-range groups
#define RMAX 6272         // max nodes per group (ceil(50000/8)=6250)

typedef unsigned int uint;
typedef unsigned short ushort;

// round-to-nearest-even fp32 -> bf16 (pair packed into a uint)
__device__ __forceinline__ uint f2bf2(float a, float b) {
  uint ua = __float_as_uint(a);
  uint ub = __float_as_uint(b);
  ua += 0x7fffu + ((ua >> 16) & 1u);
  ub += 0x7fffu + ((ub >> 16) & 1u);
  return (ua >> 16) | (ub & 0xffff0000u);
}

// ---------------- weight transpose (k-major) ----------------
__global__ __launch_bounds__(256) void transpose_kernel(
    const float* __restrict__ fw, const float* __restrict__ rootw,
    const float* __restrict__ lin1, const float* __restrict__ lin2,
    float* __restrict__ fwT, float* __restrict__ wrT,
    float* __restrict__ w1T, float* __restrict__ w2T) {
  int e = blockIdx.x * 256 + threadIdx.x;
  if (e < 16384) {
    int o = e >> 8, k = e & 255;
    fwT[k * 64 + o] = fw[e];
  }
  int e2 = e - 16384;
  if (e2 >= 0 && e2 < 12288) {
    int l = e2 >> 12, r = e2 & 4095;
    int o = r >> 6, k = r & 63;
    size_t t = (size_t)l * 4096 + k * 64 + o;
    wrT[t] = rootw[e2];
    w1T[t] = lin1[e2];
    w2T[t] = lin2[e2];
  }
}

// ---------------- x -> bf16 table ----------------
__global__ __launch_bounds__(256) void convx_kernel(
    const float* __restrict__ x, uint* __restrict__ xb, int n4) {
  int e = blockIdx.x * 256 + threadIdx.x;
  if (e >= n4) return;
  float4 v = ((const float4*)x)[e];
  uint2 o;
  o.x = f2bf2(v.x, v.y);
  o.y = f2bf2(v.z, v.w);
  ((uint2*)xb)[e] = o;
}

// ---------------- CSR build: atomic-free chunked counting sort ----------------
// hist: grid (c=NCHK, g=NGRP, z=2). z=0: dst keys -> Hd; z=1: src keys -> Hs.
// One 25 KB LDS histogram per block. linear%8 = c%8 -> chunk L2-local.
__global__ __launch_bounds__(256) void hist_kernel(
    const int* __restrict__ src, const int* __restrict__ dst,
    int* __restrict__ Hd, int* __restrict__ Hs, int E, int N, int chunk) {
  int c = blockIdx.x, g = blockIdx.y, z = blockIdx.z;
  const int* key = z ? src : dst;
  int* H = z ? Hs : Hd;
  int lo = (int)((long long)N * g / NGRP);
  int hi = (int)((long long)N * (g + 1) / NGRP);
  int range = hi - lo;
  __shared__ int cnt[RMAX];
  for (int i = threadIdx.x; i < range; i += 256) cnt[i] = 0;
  __syncthreads();
  int e0 = c * chunk, e1 = min(E, e0 + chunk);
  for (int e = e0 + (int)threadIdx.x * 4; e < e1; e += 1024) {
    if (e + 4 <= e1) {
      int4 k4 = *(const int4*)(key + e);
      if (k4.x >= lo && k4.x < hi) atomicAdd(&cnt[k4.x - lo], 1);
      if (k4.y >= lo && k4.y < hi) atomicAdd(&cnt[k4.y - lo], 1);
      if (k4.z >= lo && k4.z < hi) atomicAdd(&cnt[k4.z - lo], 1);
      if (k4.w >= lo && k4.w < hi) atomicAdd(&cnt[k4.w - lo], 1);
    } else {
      for (int k = e; k < e1; ++k) {
        int v = key[k];
        if (v >= lo && v < hi) atomicAdd(&cnt[v - lo], 1);
      }
    }
  }
  __syncthreads();
  for (int i = threadIdx.x; i < range; i += 256)
    H[(size_t)c * N + lo + i] = cnt[i];
}

__global__ __launch_bounds__(256) void degsum_kernel(
    const int* __restrict__ Hd, const int* __restrict__ Hs,
    int* __restrict__ deg_d, int* __restrict__ deg_s, int N) {
  int n = blockIdx.x * 256 + threadIdx.x;
  if (n >= N) return;
  int sd = 0, ss = 0;
#pragma unroll
  for (int c = 0; c < NCHK; ++c) {
    sd += Hd[(size_t)c * N + n];
    ss += Hs[(size_t)c * N + n];
  }
  deg_d[n] = sd;
  deg_s[n] = ss;
}

__global__ __launch_bounds__(256) void scan_partial(
    const int* __restrict__ deg_d, const int* __restrict__ deg_s,
    int* __restrict__ bsum, int n, int nb) {
  const int* deg = (blockIdx.y == 0) ? deg_d : deg_s;
  int tid = threadIdx.x;
  int base = blockIdx.x * SCAN_ELEMS;
  int s = 0;
#pragma unroll
  for (int j = 0; j < 8; ++j) {
    int i = base + j * 256 + tid;
    if (i < n) s += deg[i];
  }
#pragma unroll
  for (int off = 1; off < 64; off <<= 1) s += __shfl_xor(s, off);
  __shared__ int ws[4];
  if ((tid & 63) == 0) ws[tid >> 6] = s;
  __syncthreads();
  if (tid == 0) bsum[blockIdx.y * nb + blockIdx.x] = ws[0] + ws[1] + ws[2] + ws[3];
}

__global__ __launch_bounds__(256) void scan_bsum(int* __restrict__ bsum, int nb) {
  __shared__ int sh[256];
  int tid = threadIdx.x;
  for (int h = 0; h < 2; ++h) {
    int v = (tid < nb) ? bsum[h * nb + tid] : 0;
    sh[tid] = v;
    __syncthreads();
    for (int off = 1; off < 256; off <<= 1) {
      int t = (tid >= off) ? sh[tid - off] : 0;
      __syncthreads();
      sh[tid] += t;
      __syncthreads();
    }
    if (tid < nb) bsum[h * nb + tid] = sh[tid] - v;  // exclusive
    __syncthreads();
  }
}

__global__ __launch_bounds__(256) void scan_final(
    const int* __restrict__ deg_d, const int* __restrict__ deg_s,
    const int* __restrict__ bsum,
    int* __restrict__ row_d, int* __restrict__ row_s, int n, int nb) {
  const int* deg = (blockIdx.y == 0) ? deg_d : deg_s;
  int* row = (blockIdx.y == 0) ? row_d : row_s;
  int tid = threadIdx.x;
  int lane = tid & 63;
  int e0 = blockIdx.x * SCAN_ELEMS + tid * 8;
  int v[8];
  int s = 0;
#pragma unroll
  for (int j = 0; j < 8; ++j) {
    int i = e0 + j;
    v[j] = (i < n) ? deg[i] : 0;
    s += v[j];
  }
  int incl = s;
#pragma unroll
  for (int off = 1; off < 64; off <<= 1) {
    int t = __shfl_up(incl, off);
    if (lane >= off) incl += t;
  }
  __shared__ int wsum[4];
  if (lane == 63) wsum[tid >> 6] = incl;
  __syncthreads();
  int woff = 0;
  int w = tid >> 6;
  for (int k = 0; k < 4; ++k)
    if (k < w) woff += wsum[k];
  int run = incl - s + woff + bsum[blockIdx.y * nb + blockIdx.x];
#pragma unroll
  for (int j = 0; j < 8; ++j) {
    int i = e0 + j;
    if (i <= n) row[i] = run;
    run += v[j];
  }
}

__global__ __launch_bounds__(256) void cursor_kernel(
    int* __restrict__ Hd, int* __restrict__ Hs,
    const int* __restrict__ row_d, const int* __restrict__ row_s, int N) {
  int n = blockIdx.x * 256 + threadIdx.x;
  if (n >= N) return;
  int rd = row_d[n], rs = row_s[n];
#pragma unroll
  for (int c = 0; c < NCHK; ++c) {
    int t = Hd[(size_t)c * N + n]; Hd[(size_t)c * N + n] = rd; rd += t;
    t = Hs[(size_t)c * N + n];     Hs[(size_t)c * N + n] = rs; rs += t;
  }
}

// scatter: grid (g=NGRP, c=NCHK, z=2). linear%8 = g -> single-writer XCD per
// col region. z selects direction; 25 KB LDS cursor slice per block.
__global__ __launch_bounds__(256) void scatter_kernel(
    const int* __restrict__ src, const int* __restrict__ dst,
    const int* __restrict__ Hd, const int* __restrict__ Hs,
    int* __restrict__ col_d, int* __restrict__ col_s, int E, int N, int chunk) {
  int g = blockIdx.x, c = blockIdx.y, z = blockIdx.z;
  const int* key = z ? src : dst;
  const int* val = z ? dst : src;
  const int* H = z ? Hs : Hd;
  int* colp = z ? col_s : col_d;
  int lo = (int)((long long)N * g / NGRP);
  int hi = (int)((long long)N * (g + 1) / NGRP);
  int range = hi - lo;
  __shared__ int cur[RMAX];
  for (int i = threadIdx.x; i < range; i += 256)
    cur[i] = H[(size_t)c * N + lo + i];
  __syncthreads();
  int e0 = c * chunk, e1 = min(E, e0 + chunk);
  for (int e = e0 + (int)threadIdx.x * 4; e < e1; e += 1024) {
    if (e + 4 <= e1) {
      int4 k4 = *(const int4*)(key + e);
      int4 v4 = *(const int4*)(val + e);
      if (k4.x >= lo && k4.x < hi) { int p = atomicAdd(&cur[k4.x - lo], 1); colp[p] = v4.x; }
      if (k4.y >= lo && k4.y < hi) { int p = atomicAdd(&cur[k4.y - lo], 1); colp[p] = v4.y; }
      if (k4.z >= lo && k4.z < hi) { int p = atomicAdd(&cur[k4.z - lo], 1); colp[p] = v4.z; }
      if (k4.w >= lo && k4.w < hi) { int p = atomicAdd(&cur[k4.w - lo], 1); colp[p] = v4.w; }
    } else {
      for (int k = e; k < e1; ++k) {
        int kk = key[k], vv = val[k];
        if (kk >= lo && kk < hi) { int p = atomicAdd(&cur[kk - lo], 1); colp[p] = vv; }
      }
    }
  }
}

// ---------------- aggregation (bf16, 8 neighbors per load instruction) ----------------
// Lane g=lane>>3 owns neighbor slot g, fl=lane&7 owns features [fl*8,fl*8+8).
// One global_load_dwordx4 per wave fetches 8 full bf16 rows (16B/lane).
// Cross-slot reduce: shfl_xor 8/16/32; lanes g==0 store the fp32 mean row.

#define UNPACK_ACC(A, U) {                                                   \
    A[0] += __uint_as_float((U).x << 16);                                    \
    A[1] += __uint_as_float((U).x & 0xffff0000u);                            \
    A[2] += __uint_as_float((U).y << 16);                                    \
    A[3] += __uint_as_float((U).y & 0xffff0000u);                            \
    A[4] += __uint_as_float((U).z << 16);                                    \
    A[5] += __uint_as_float((U).z & 0xffff0000u);                            \
    A[6] += __uint_as_float((U).w << 16);                                    \
    A[7] += __uint_as_float((U).w & 0xffff0000u); }

__global__ __launch_bounds__(256) void agg8_kernel(
    const ushort* __restrict__ hB,
    const int* __restrict__ row_d, const int* __restrict__ col_d, float* __restrict__ g1,
    const int* __restrict__ row_s, const int* __restrict__ col_s, float* __restrict__ g2,
    int N) {
  const int* row = (blockIdx.y == 0) ? row_d : row_s;
  const int* col = (blockIdx.y == 0) ? col_d : col_s;
  float* outp = (blockIdx.y == 0) ? g1 : g2;
  int wid = blockIdx.x * 4 + (threadIdx.x >> 6);
  int lane = threadIdx.x & 63;
  int g = lane >> 3;
  int fl = lane & 7;
  if (wid >= N) return;
  int s0 = row[wid], s1 = row[wid + 1];
  const ushort* tab = hB + fl * 8;
  float a[8] = {0.f, 0.f, 0.f, 0.f, 0.f, 0.f, 0.f, 0.f};
  float b[8] = {0.f, 0.f, 0.f, 0.f, 0.f, 0.f, 0.f, 0.f};
  int p = s0;
  for (; p + 16 <= s1; p += 16) {
    int n0 = col[p + g];
    int n1 = col[p + 8 + g];
    uint4 u0 = *(const uint4*)(tab + (size_t)n0 * 64);
    uint4 u1 = *(const uint4*)(tab + (size_t)n1 * 64);
    UNPACK_ACC(a, u0);
    UNPACK_ACC(b, u1);
  }
  if (p + 8 <= s1) {
    int n = col[p + g];
    uint4 u = *(const uint4*)(tab + (size_t)n * 64);
    UNPACK_ACC(a, u);
    p += 8;
  }
  if (p + g < s1) {
    int n = col[p + g];
    uint4 u = *(const uint4*)(tab + (size_t)n * 64);
    UNPACK_ACC(b, u);
  }
#pragma unroll
  for (int i = 0; i < 8; ++i) a[i] += b[i];
#pragma unroll
  for (int i = 0; i < 8; ++i) {
    a[i] += __shfl_xor(a[i], 8);
    a[i] += __shfl_xor(a[i], 16);
    a[i] += __shfl_xor(a[i], 32);
  }
  int cnt = s1 - s0;
  float inv = cnt > 0 ? 1.f / (float)cnt : 0.f;
  if (g == 0) {
    float4 v0; v0.x = a[0]*inv; v0.y = a[1]*inv; v0.z = a[2]*inv; v0.w = a[3]*inv;
    float4 v1; v1.x = a[4]*inv; v1.y = a[5]*inv; v1.z = a[6]*inv; v1.w = a[7]*inv;
    float4* op = (float4*)(outp + (size_t)wid * NDIM + fl * 8);
    op[0] = v0;
    op[1] = v1;
  }
}

// ---------------- combine: 64-node LDS tile, lane=node, wave=16 outputs ----------------

__global__ __launch_bounds__(256, 3) void combine_kernel(
    const float* __restrict__ h, const float* __restrict__ g1,
    const float* __restrict__ g2, const float* __restrict__ wrT,
    const float* __restrict__ w1T, const float* __restrict__ w2T,
    const float* __restrict__ bias, float* __restrict__ hout,
    ushort* __restrict__ hbout, int N) {
  __shared__ float Ht[64][65];
  __shared__ float G1t[64][65];
  __shared__ float G2t[64][65];
  int tid = threadIdx.x;
  int n0 = blockIdx.x * 64;
  int r = tid >> 2;
  bool ok = (n0 + r) < N;
  const float4* hp = (const float4*)(h  + (size_t)(n0 + r) * NDIM);
  const float4* q1 = (const float4*)(g1 + (size_t)(n0 + r) * NDIM);
  const float4* q2 = (const float4*)(g2 + (size_t)(n0 + r) * NDIM);
#pragma unroll
  for (int i = 0; i < 4; ++i) {
    int q = (tid & 3) + i * 4;
    float4 a = ok ? hp[q] : float4{0.f, 0.f, 0.f, 0.f};
    float4 b = ok ? q1[q] : float4{0.f, 0.f, 0.f, 0.f};
    float4 c = ok ? q2[q] : float4{0.f, 0.f, 0.f, 0.f};
    Ht[r][q*4+0]=a.x;  Ht[r][q*4+1]=a.y;  Ht[r][q*4+2]=a.z;  Ht[r][q*4+3]=a.w;
    G1t[r][q*4+0]=b.x; G1t[r][q*4+1]=b.y; G1t[r][q*4+2]=b.z; G1t[r][q*4+3]=b.w;
    G2t[r][q*4+0]=c.x; G2t[r][q*4+1]=c.y; G2t[r][q*4+2]=c.z; G2t[r][q*4+3]=c.w;
  }
  __syncthreads();
  int w = __builtin_amdgcn_readfirstlane(tid >> 6);
  int lane = tid & 63;
  int ob = w * 16;
  float acc[16];
#pragma unroll
  for (int o = 0; o < 16; ++o) acc[o] = bias[ob + o];
  float4 nA[4], nB[4], nC[4];
  float nh, n1v, n2v;
  {
    const float4* pa = (const float4*)(wrT + ob);
    const float4* pb = (const float4*)(w1T + ob);
    const float4* pc = (const float4*)(w2T + ob);
#pragma unroll
    for (int j = 0; j < 4; ++j) { nA[j] = pa[j]; nB[j] = pb[j]; nC[j] = pc[j]; }
    nh = Ht[lane][0]; n1v = G1t[lane][0]; n2v = G2t[lane][0];
  }
  for (int k = 0; k < 64; ++k) {
    float4 A[4], B[4], C[4];
    float hv = nh, v1 = n1v, v2 = n2v;
#pragma unroll
    for (int j = 0; j < 4; ++j) { A[j] = nA[j]; B[j] = nB[j]; C[j] = nC[j]; }
    if (k < 63) {
      int k1 = k + 1;
      const float4* pa = (const float4*)(wrT + k1 * 64 + ob);
      const float4* pb = (const float4*)(w1T + k1 * 64 + ob);
      const float4* pc = (const float4*)(w2T + k1 * 64 + ob);
#pragma unroll
      for (int j = 0; j < 4; ++j) { nA[j] = pa[j]; nB[j] = pb[j]; nC[j] = pc[j]; }
      nh = Ht[lane][k1]; n1v = G1t[lane][k1]; n2v = G2t[lane][k1];
    }
#pragma unroll
    for (int j = 0; j < 4; ++j) {
      acc[4*j+0] += hv * A[j].x + v1 * B[j].x + v2 * C[j].x;
      acc[4*j+1] += hv * A[j].y + v1 * B[j].y + v2 * C[j].y;
      acc[4*j+2] += hv * A[j].z + v1 * B[j].z + v2 * C[j].z;
      acc[4*j+3] += hv * A[j].w + v1 * B[j].w + v2 * C[j].w;
    }
  }
  int node = n0 + lane;
  if (node < N) {
    float rl[16];
#pragma unroll
    for (int o = 0; o < 16; ++o) rl[o] = fmaxf(acc[o], 0.f);
    float4* op = (float4*)(hout + (size_t)node * NDIM + ob);
#pragma unroll
    for (int j = 0; j < 4; ++j) {
      float4 v;
      v.x = rl[4*j+0]; v.y = rl[4*j+1]; v.z = rl[4*j+2]; v.w = rl[4*j+3];
      op[j] = v;
    }
    if (hbout) {
      uint4 u0, u1;
      u0.x = f2bf2(rl[0],  rl[1]);  u0.y = f2bf2(rl[2],  rl[3]);
      u0.z = f2bf2(rl[4],  rl[5]);  u0.w = f2bf2(rl[6],  rl[7]);
      u1.x = f2bf2(rl[8],  rl[9]);  u1.y = f2bf2(rl[10], rl[11]);
      u1.z = f2bf2(rl[12], rl[13]); u1.w = f2bf2(rl[14], rl[15]);
      uint4* bp = (uint4*)(hbout + (size_t)node * NDIM + ob);
      bp[0] = u0; bp[1] = u1;
    }
  }
}

// ---------------- final: 64-node LDS tile (4 input bufs), lane=node ----------------

__global__ __launch_bounds__(256, 2) void final_kernel(
    const float* __restrict__ x, const float* __restrict__ h1,
    const float* __restrict__ h2, const float* __restrict__ h3,
    const float* __restrict__ fwT, const float* __restrict__ fb,
    float* __restrict__ outp, int N) {
  __shared__ float Ft[4][64][65];
  int tid = threadIdx.x;
  int n0 = blockIdx.x * 64;
  int r = tid >> 2;
  bool ok = (n0 + r) < N;
  const float* bufs[4] = {x, h1, h2, h3};
#pragma unroll
  for (int b = 0; b < 4; ++b) {
    const float4* ip = (const float4*)(bufs[b] + (size_t)(n0 + r) * NDIM);
#pragma unroll
    for (int i = 0; i < 4; ++i) {
      int q = (tid & 3) + i * 4;
      float4 v = ok ? ip[q] : float4{0.f, 0.f, 0.f, 0.f};
      Ft[b][r][q*4+0]=v.x; Ft[b][r][q*4+1]=v.y; Ft[b][r][q*4+2]=v.z; Ft[b][r][q*4+3]=v.w;
    }
  }
  __syncthreads();
  int w = __builtin_amdgcn_readfirstlane(tid >> 6);
  int lane = tid & 63;
  int ob = w * 16;
  float acc[16];
#pragma unroll
  for (int o = 0; o < 16; ++o) acc[o] = fb[ob + o];
  float4 nW[4];
  float nv;
  {
    const float4* wp = (const float4*)(fwT + ob);
#pragma unroll
    for (int j = 0; j < 4; ++j) nW[j] = wp[j];
    nv = Ft[0][lane][0];
  }
  for (int k = 0; k < 256; ++k) {
    float4 W[4];
    float v = nv;
#pragma unroll
    for (int j = 0; j < 4; ++j) W[j] = nW[j];
    if (k < 255) {
      int k1 = k + 1;
      const float4* wp = (const float4*)(fwT + k1 * 64 + ob);
#pragma unroll
      for (int j = 0; j < 4; ++j) nW[j] = wp[j];
      nv = Ft[k1 >> 6][lane][k1 & 63];
    }
#pragma unroll
    for (int j = 0; j < 4; ++j) {
      acc[4*j+0] += v * W[j].x;
      acc[4*j+1] += v * W[j].y;
      acc[4*j+2] += v * W[j].z;
      acc[4*j+3] += v * W[j].w;
    }
  }
  int node = n0 + lane;
  if (node < N) {
    float4* op = (float4*)(outp + (size_t)node * NDIM + ob);
#pragma unroll
    for (int j = 0; j < 4; ++j) {
      float4 v;
      v.x = acc[4*j+0]; v.y = acc[4*j+1]; v.z = acc[4*j+2]; v.w = acc[4*j+3];
      op[j] = v;
    }
  }
}

// ---------------- launch ----------------

extern "C" void kernel_launch(void* const* d_in, const int* in_sizes, int n_in,
                              void* d_out, int out_size, void* d_ws, size_t ws_size,
                              hipStream_t stream) {
  const float* x     = (const float*)d_in[0];
  const int*   ei    = (const int*)d_in[1];
  const float* lin1  = (const float*)d_in[2];
  const float* lin2  = (const float*)d_in[3];
  const float* rootw = (const float*)d_in[4];
  const float* rootb = (const float*)d_in[5];
  const float* fw    = (const float*)d_in[6];
  const float* fb    = (const float*)d_in[7];
  float* out = (float*)d_out;

  int N = in_sizes[0] / NDIM;
  int E = in_sizes[1] / 2;
  const int* src = ei;
  const int* dst = ei + E;

  int* ip = (int*)d_ws;
  int* Hd    = ip; ip += (size_t)NCHK * N;
  int* Hs    = ip; ip += (size_t)NCHK * N;
  int* deg_d = ip; ip += N;
  int* deg_s = ip; ip += N;
  int* row_d = ip; ip += N + 1;
  int* row_s = ip; ip += N + 1;
  int* bsum  = ip; ip += 256;
  int* col_d = ip; ip += E;
  int* col_s = ip; ip += E;
  uintptr_t fbase = (((uintptr_t)ip) + 255) & ~(uintptr_t)255;
  float* fwT = (float*)fbase;
  float* wrT = fwT + 16384;
  float* w1T = wrT + 12288;
  float* w2T = w1T + 12288;
  float* h1  = w2T + 12288;
  float* h2 = h1 + (size_t)N * NDIM;
  float* h3 = h2 + (size_t)N * NDIM;
  float* g1 = h3 + (size_t)N * NDIM;
  float* g2 = g1 + (size_t)N * NDIM;
  ushort* hB0 = (ushort*)(g2 + (size_t)N * NDIM);
  ushort* hB1 = hB0 + (size_t)N * NDIM;
  ushort* hB2 = hB1 + (size_t)N * NDIM;

  int chunk = (E + NCHK - 1) / NCHK;
  int nb = (N + SCAN_ELEMS - 1) / SCAN_ELEMS;
  int nblk = (N + 255) / 256;

  transpose_kernel<<<112, 256, 0, stream>>>(fw, rootw, lin1, lin2, fwT, wrT, w1T, w2T);
  convx_kernel<<<(N * 16 + 255) / 256, 256, 0, stream>>>(x, (uint*)hB0, N * 16);
  hist_kernel<<<dim3(NCHK, NGRP, 2), 256, 0, stream>>>(src, dst, Hd, Hs, E, N, chunk);
  degsum_kernel<<<nblk, 256, 0, stream>>>(Hd, Hs, deg_d, deg_s, N);
  scan_partial<<<dim3(nb, 2), 256, 0, stream>>>(deg_d, deg_s, bsum, N, nb);
  scan_bsum<<<1, 256, 0, stream>>>(bsum, nb);
  scan_final<<<dim3(nb, 2), 256, 0, stream>>>(deg_d, deg_s, bsum, row_d, row_s, N, nb);
  cursor_kernel<<<nblk, 256, 0, stream>>>(Hd, Hs, row_d, row_s, N);
  scatter_kernel<<<dim3(NGRP, NCHK, 2), 256, 0, stream>>>(src, dst, Hd, Hs,
                                                          col_d, col_s, E, N, chunk);

  int ab = (N + 3) / 4;
  int tgrid = (N + 63) / 64;
  const float*  hbufs[4]  = {x, h1, h2, h3};
  const ushort* hBbufs[3] = {hB0, hB1, hB2};
  for (int l = 0; l < 3; ++l) {
    agg8_kernel<<<dim3(ab, 2), 256, 0, stream>>>(hBbufs[l], row_d, col_d, g1,
                                                 row_s, col_s, g2, N);
    ushort* hbnext = (l < 2) ? (ushort*)hBbufs[l + 1] : (ushort*)nullptr;
    combine_kernel<<<tgrid, 256, 0, stream>>>(hbufs[l], g1, g2,
                                              wrT + (size_t)l * 4096,
                                              w1T + (size_t)l * 4096,
                                              w2T + (size_t)l * 4096,
                                              rootb + (size_t)l * 64,
                                              (float*)hbufs[l + 1], hbnext, N);
  }
  final_kernel<<<tgrid, 256, 0, stream>>>(x, h1, h2, h3, fwT, fb, out, N);
}

// Round 12
// 310.276 us; speedup vs baseline: 1.6806x; 1.1945x over previous
//
#include <hip/hip_runtime.h>
#include <stdint.h>

#define NDIM 64
#define SCAN_ELEMS 2048   // elements per scan block (256 thr x 8)
#define NCHK 32           // edge chunks
#define NGRP 8            // node-range groups
#define RMAX 6272         // max nodes per group (ceil(50000/8)=6250)

typedef unsigned int uint;
typedef unsigned short ushort;

// round-to-nearest-even fp32 -> bf16 (pair packed into a uint)
__device__ __forceinline__ uint f2bf2(float a, float b) {
  uint ua = __float_as_uint(a);
  uint ub = __float_as_uint(b);
  ua += 0x7fffu + ((ua >> 16) & 1u);
  ub += 0x7fffu + ((ub >> 16) & 1u);
  return (ua >> 16) | (ub & 0xffff0000u);
}
__device__ __forceinline__ float bflo(uint u) { return __uint_as_float(u << 16); }
__device__ __forceinline__ float bfhi(uint u) { return __uint_as_float(u & 0xffff0000u); }

// ---------------- weight transpose (k-major) ----------------
__global__ __launch_bounds__(256) void transpose_kernel(
    const float* __restrict__ fw, const float* __restrict__ rootw,
    const float* __restrict__ lin1, const float* __restrict__ lin2,
    float* __restrict__ fwT, float* __restrict__ wrT,
    float* __restrict__ w1T, float* __restrict__ w2T) {
  int e = blockIdx.x * 256 + threadIdx.x;
  if (e < 16384) {
    int o = e >> 8, k = e & 255;
    fwT[k * 64 + o] = fw[e];
  }
  int e2 = e - 16384;
  if (e2 >= 0 && e2 < 12288) {
    int l = e2 >> 12, r = e2 & 4095;
    int o = r >> 6, k = r & 63;
    size_t t = (size_t)l * 4096 + k * 64 + o;
    wrT[t] = rootw[e2];
    w1T[t] = lin1[e2];
    w2T[t] = lin2[e2];
  }
}

// ---------------- x -> bf16 table ----------------
__global__ __launch_bounds__(256) void convx_kernel(
    const float* __restrict__ x, uint* __restrict__ xb, int n4) {
  int e = blockIdx.x * 256 + threadIdx.x;
  if (e >= n4) return;
  float4 v = ((const float4*)x)[e];
  uint2 o;
  o.x = f2bf2(v.x, v.y);
  o.y = f2bf2(v.z, v.w);
  ((uint2*)xb)[e] = o;
}

// ---------------- CSR build: atomic-free chunked counting sort ----------------
__global__ __launch_bounds__(256) void hist_kernel(
    const int* __restrict__ src, const int* __restrict__ dst,
    int* __restrict__ Hd, int* __restrict__ Hs, int E, int N, int chunk) {
  int c = blockIdx.x, g = blockIdx.y, z = blockIdx.z;
  const int* key = z ? src : dst;
  int* H = z ? Hs : Hd;
  int lo = (int)((long long)N * g / NGRP);
  int hi = (int)((long long)N * (g + 1) / NGRP);
  int range = hi - lo;
  __shared__ int cnt[RMAX];
  for (int i = threadIdx.x; i < range; i += 256) cnt[i] = 0;
  __syncthreads();
  int e0 = c * chunk, e1 = min(E, e0 + chunk);
  for (int e = e0 + (int)threadIdx.x * 4; e < e1; e += 1024) {
    if (e + 4 <= e1) {
      int4 k4 = *(const int4*)(key + e);
      if (k4.x >= lo && k4.x < hi) atomicAdd(&cnt[k4.x - lo], 1);
      if (k4.y >= lo && k4.y < hi) atomicAdd(&cnt[k4.y - lo], 1);
      if (k4.z >= lo && k4.z < hi) atomicAdd(&cnt[k4.z - lo], 1);
      if (k4.w >= lo && k4.w < hi) atomicAdd(&cnt[k4.w - lo], 1);
    } else {
      for (int k = e; k < e1; ++k) {
        int v = key[k];
        if (v >= lo && v < hi) atomicAdd(&cnt[v - lo], 1);
      }
    }
  }
  __syncthreads();
  for (int i = threadIdx.x; i < range; i += 256)
    H[(size_t)c * N + lo + i] = cnt[i];
}

__global__ __launch_bounds__(256) void degsum_kernel(
    const int* __restrict__ Hd, const int* __restrict__ Hs,
    int* __restrict__ deg_d, int* __restrict__ deg_s, int N) {
  int n = blockIdx.x * 256 + threadIdx.x;
  if (n >= N) return;
  int sd = 0, ss = 0;
#pragma unroll
  for (int c = 0; c < NCHK; ++c) {
    sd += Hd[(size_t)c * N + n];
    ss += Hs[(size_t)c * N + n];
  }
  deg_d[n] = sd;
  deg_s[n] = ss;
}

__global__ __launch_bounds__(256) void scan_partial(
    const int* __restrict__ deg_d, const int* __restrict__ deg_s,
    int* __restrict__ bsum, int n, int nb) {
  const int* deg = (blockIdx.y == 0) ? deg_d : deg_s;
  int tid = threadIdx.x;
  int base = blockIdx.x * SCAN_ELEMS;
  int s = 0;
#pragma unroll
  for (int j = 0; j < 8; ++j) {
    int i = base + j * 256 + tid;
    if (i < n) s += deg[i];
  }
#pragma unroll
  for (int off = 1; off < 64; off <<= 1) s += __shfl_xor(s, off);
  __shared__ int ws[4];
  if ((tid & 63) == 0) ws[tid >> 6] = s;
  __syncthreads();
  if (tid == 0) bsum[blockIdx.y * nb + blockIdx.x] = ws[0] + ws[1] + ws[2] + ws[3];
}

__global__ __launch_bounds__(256) void scan_bsum(int* __restrict__ bsum, int nb) {
  __shared__ int sh[256];
  int tid = threadIdx.x;
  for (int h = 0; h < 2; ++h) {
    int v = (tid < nb) ? bsum[h * nb + tid] : 0;
    sh[tid] = v;
    __syncthreads();
    for (int off = 1; off < 256; off <<= 1) {
      int t = (tid >= off) ? sh[tid - off] : 0;
      __syncthreads();
      sh[tid] += t;
      __syncthreads();
    }
    if (tid < nb) bsum[h * nb + tid] = sh[tid] - v;  // exclusive
    __syncthreads();
  }
}

__global__ __launch_bounds__(256) void scan_final(
    const int* __restrict__ deg_d, const int* __restrict__ deg_s,
    const int* __restrict__ bsum,
    int* __restrict__ row_d, int* __restrict__ row_s, int n, int nb) {
  const int* deg = (blockIdx.y == 0) ? deg_d : deg_s;
  int* row = (blockIdx.y == 0) ? row_d : row_s;
  int tid = threadIdx.x;
  int lane = tid & 63;
  int e0 = blockIdx.x * SCAN_ELEMS + tid * 8;
  int v[8];
  int s = 0;
#pragma unroll
  for (int j = 0; j < 8; ++j) {
    int i = e0 + j;
    v[j] = (i < n) ? deg[i] : 0;
    s += v[j];
  }
  int incl = s;
#pragma unroll
  for (int off = 1; off < 64; off <<= 1) {
    int t = __shfl_up(incl, off);
    if (lane >= off) incl += t;
  }
  __shared__ int wsum[4];
  if (lane == 63) wsum[tid >> 6] = incl;
  __syncthreads();
  int woff = 0;
  int w = tid >> 6;
  for (int k = 0; k < 4; ++k)
    if (k < w) woff += wsum[k];
  int run = incl - s + woff + bsum[blockIdx.y * nb + blockIdx.x];
#pragma unroll
  for (int j = 0; j < 8; ++j) {
    int i = e0 + j;
    if (i <= n) row[i] = run;
    run += v[j];
  }
}

__global__ __launch_bounds__(256) void cursor_kernel(
    int* __restrict__ Hd, int* __restrict__ Hs,
    const int* __restrict__ row_d, const int* __restrict__ row_s, int N) {
  int n = blockIdx.x * 256 + threadIdx.x;
  if (n >= N) return;
  int rd = row_d[n], rs = row_s[n];
#pragma unroll
  for (int c = 0; c < NCHK; ++c) {
    int t = Hd[(size_t)c * N + n]; Hd[(size_t)c * N + n] = rd; rd += t;
    t = Hs[(size_t)c * N + n];     Hs[(size_t)c * N + n] = rs; rs += t;
  }
}

__global__ __launch_bounds__(256) void scatter_kernel(
    const int* __restrict__ src, const int* __restrict__ dst,
    const int* __restrict__ Hd, const int* __restrict__ Hs,
    int* __restrict__ col_d, int* __restrict__ col_s, int E, int N, int chunk) {
  int g = blockIdx.x, c = blockIdx.y, z = blockIdx.z;
  const int* key = z ? src : dst;
  const int* val = z ? dst : src;
  const int* H = z ? Hs : Hd;
  int* colp = z ? col_s : col_d;
  int lo = (int)((long long)N * g / NGRP);
  int hi = (int)((long long)N * (g + 1) / NGRP);
  int range = hi - lo;
  __shared__ int cur[RMAX];
  for (int i = threadIdx.x; i < range; i += 256)
    cur[i] = H[(size_t)c * N + lo + i];
  __syncthreads();
  int e0 = c * chunk, e1 = min(E, e0 + chunk);
  for (int e = e0 + (int)threadIdx.x * 4; e < e1; e += 1024) {
    if (e + 4 <= e1) {
      int4 k4 = *(const int4*)(key + e);
      int4 v4 = *(const int4*)(val + e);
      if (k4.x >= lo && k4.x < hi) { int p = atomicAdd(&cur[k4.x - lo], 1); colp[p] = v4.x; }
      if (k4.y >= lo && k4.y < hi) { int p = atomicAdd(&cur[k4.y - lo], 1); colp[p] = v4.y; }
      if (k4.z >= lo && k4.z < hi) { int p = atomicAdd(&cur[k4.z - lo], 1); colp[p] = v4.z; }
      if (k4.w >= lo && k4.w < hi) { int p = atomicAdd(&cur[k4.w - lo], 1); colp[p] = v4.w; }
    } else {
      for (int k = e; k < e1; ++k) {
        int kk = key[k], vv = val[k];
        if (kk >= lo && kk < hi) { int p = atomicAdd(&cur[kk - lo], 1); colp[p] = vv; }
      }
    }
  }
}

// ---------------- aggregation (bf16 in, bf16 out; 8 neighbors per load) ----------------

#define UNPACK_ACC(A, U) {                                                   \
    A[0] += __uint_as_float((U).x << 16);                                    \
    A[1] += __uint_as_float((U).x & 0xffff0000u);                            \
    A[2] += __uint_as_float((U).y << 16);                                    \
    A[3] += __uint_as_float((U).y & 0xffff0000u);                            \
    A[4] += __uint_as_float((U).z << 16);                                    \
    A[5] += __uint_as_float((U).z & 0xffff0000u);                            \
    A[6] += __uint_as_float((U).w << 16);                                    \
    A[7] += __uint_as_float((U).w & 0xffff0000u); }

__global__ __launch_bounds__(256) void agg8_kernel(
    const ushort* __restrict__ hB,
    const int* __restrict__ row_d, const int* __restrict__ col_d, ushort* __restrict__ g1,
    const int* __restrict__ row_s, const int* __restrict__ col_s, ushort* __restrict__ g2,
    int N) {
  const int* row = (blockIdx.y == 0) ? row_d : row_s;
  const int* col = (blockIdx.y == 0) ? col_d : col_s;
  ushort* outp = (blockIdx.y == 0) ? g1 : g2;
  int wid = blockIdx.x * 4 + (threadIdx.x >> 6);
  int lane = threadIdx.x & 63;
  int g = lane >> 3;
  int fl = lane & 7;
  if (wid >= N) return;
  int s0 = row[wid], s1 = row[wid + 1];
  const ushort* tab = hB + fl * 8;
  float a[8] = {0.f, 0.f, 0.f, 0.f, 0.f, 0.f, 0.f, 0.f};
  float b[8] = {0.f, 0.f, 0.f, 0.f, 0.f, 0.f, 0.f, 0.f};
  int p = s0;
  for (; p + 16 <= s1; p += 16) {
    int n0 = col[p + g];
    int n1 = col[p + 8 + g];
    uint4 u0 = *(const uint4*)(tab + (size_t)n0 * 64);
    uint4 u1 = *(const uint4*)(tab + (size_t)n1 * 64);
    UNPACK_ACC(a, u0);
    UNPACK_ACC(b, u1);
  }
  if (p + 8 <= s1) {
    int n = col[p + g];
    uint4 u = *(const uint4*)(tab + (size_t)n * 64);
    UNPACK_ACC(a, u);
    p += 8;
  }
  if (p + g < s1) {
    int n = col[p + g];
    uint4 u = *(const uint4*)(tab + (size_t)n * 64);
    UNPACK_ACC(b, u);
  }
#pragma unroll
  for (int i = 0; i < 8; ++i) a[i] += b[i];
#pragma unroll
  for (int i = 0; i < 8; ++i) {
    a[i] += __shfl_xor(a[i], 8);
    a[i] += __shfl_xor(a[i], 16);
    a[i] += __shfl_xor(a[i], 32);
  }
  int cnt = s1 - s0;
  float inv = cnt > 0 ? 1.f / (float)cnt : 0.f;
  if (g == 0) {
    uint4 o;
    o.x = f2bf2(a[0] * inv, a[1] * inv);
    o.y = f2bf2(a[2] * inv, a[3] * inv);
    o.z = f2bf2(a[4] * inv, a[5] * inv);
    o.w = f2bf2(a[6] * inv, a[7] * inv);
    *(uint4*)(outp + (size_t)wid * NDIM + fl * 8) = o;
  }
}

// ---------------- combine: 128-node bf16 LDS tile, 2 nodes/lane, wave=16 outputs --------
// h_out = relu([h|g1|g2] @ [R|W1|W2]^T + b), bf16 activations, fp32 weights/acc.
// Per k-pair: 24 weight-float4 loads cover 192 FMAs (8:1 issue ratio).

__global__ __launch_bounds__(256, 3) void combine_kernel(
    const ushort* __restrict__ hBin, const ushort* __restrict__ g1b,
    const ushort* __restrict__ g2b, const float* __restrict__ wrT,
    const float* __restrict__ w1T, const float* __restrict__ w2T,
    const float* __restrict__ bias, ushort* __restrict__ hbout, int N) {
  __shared__ uint Ht[128][33];
  __shared__ uint G1t[128][33];
  __shared__ uint G2t[128][33];
  int tid = threadIdx.x;
  int n0 = blockIdx.x * 128;
  {
    int r = tid >> 1, hf = tid & 1;
    int nc = min(n0 + r, N - 1);
    const uint4* ph = (const uint4*)(hBin + (size_t)nc * 64);
    const uint4* p1 = (const uint4*)(g1b + (size_t)nc * 64);
    const uint4* p2 = (const uint4*)(g2b + (size_t)nc * 64);
#pragma unroll
    for (int i = 0; i < 4; ++i) {
      int q = hf * 4 + i;
      uint4 a = ph[q], b = p1[q], c = p2[q];
      int base = q * 4;
      Ht[r][base+0]=a.x;  Ht[r][base+1]=a.y;  Ht[r][base+2]=a.z;  Ht[r][base+3]=a.w;
      G1t[r][base+0]=b.x; G1t[r][base+1]=b.y; G1t[r][base+2]=b.z; G1t[r][base+3]=b.w;
      G2t[r][base+0]=c.x; G2t[r][base+1]=c.y; G2t[r][base+2]=c.z; G2t[r][base+3]=c.w;
    }
  }
  __syncthreads();
  int w = __builtin_amdgcn_readfirstlane(tid >> 6);
  int lane = tid & 63;
  int ob = w * 16;
  float aa[16], ab[16];
#pragma unroll
  for (int o = 0; o < 16; ++o) { float bv = bias[ob + o]; aa[o] = bv; ab[o] = bv; }
  for (int kp = 0; kp < 32; ++kp) {
    uint hua = Ht[lane][kp],  hub = Ht[lane + 64][kp];
    uint gua = G1t[lane][kp], gub = G1t[lane + 64][kp];
    uint fua = G2t[lane][kp], fub = G2t[lane + 64][kp];
    float ha0 = bflo(hua), ha1 = bfhi(hua), hb0 = bflo(hub), hb1 = bfhi(hub);
    float ga0 = bflo(gua), ga1 = bfhi(gua), gb0 = bflo(gub), gb1 = bfhi(gub);
    float fa0 = bflo(fua), fa1 = bfhi(fua), fb0 = bflo(fub), fb1 = bfhi(fub);
    const float4* pa0 = (const float4*)(wrT + (2 * kp) * 64 + ob);
    const float4* pa1 = (const float4*)(wrT + (2 * kp + 1) * 64 + ob);
    const float4* pb0 = (const float4*)(w1T + (2 * kp) * 64 + ob);
    const float4* pb1 = (const float4*)(w1T + (2 * kp + 1) * 64 + ob);
    const float4* pc0 = (const float4*)(w2T + (2 * kp) * 64 + ob);
    const float4* pc1 = (const float4*)(w2T + (2 * kp + 1) * 64 + ob);
#pragma unroll
    for (int j = 0; j < 4; ++j) {
      float4 A0 = pa0[j], A1 = pa1[j];
      float4 B0 = pb0[j], B1 = pb1[j];
      float4 C0 = pc0[j], C1 = pc1[j];
      aa[4*j+0] += ha0*A0.x + ha1*A1.x + ga0*B0.x + ga1*B1.x + fa0*C0.x + fa1*C1.x;
      aa[4*j+1] += ha0*A0.y + ha1*A1.y + ga0*B0.y + ga1*B1.y + fa0*C0.y + fa1*C1.y;
      aa[4*j+2] += ha0*A0.z + ha1*A1.z + ga0*B0.z + ga1*B1.z + fa0*C0.z + fa1*C1.z;
      aa[4*j+3] += ha0*A0.w + ha1*A1.w + ga0*B0.w + ga1*B1.w + fa0*C0.w + fa1*C1.w;
      ab[4*j+0] += hb0*A0.x + hb1*A1.x + gb0*B0.x + gb1*B1.x + fb0*C0.x + fb1*C1.x;
      ab[4*j+1] += hb0*A0.y + hb1*A1.y + gb0*B0.y + gb1*B1.y + fb0*C0.y + fb1*C1.y;
      ab[4*j+2] += hb0*A0.z + hb1*A1.z + gb0*B0.z + gb1*B1.z + fb0*C0.z + fb1*C1.z;
      ab[4*j+3] += hb0*A0.w + hb1*A1.w + gb0*B0.w + gb1*B1.w + fb0*C0.w + fb1*C1.w;
    }
  }
  int na = n0 + lane, nb = n0 + 64 + lane;
  if (na < N) {
    uint4 u0, u1;
    u0.x = f2bf2(fmaxf(aa[0],0.f),  fmaxf(aa[1],0.f));
    u0.y = f2bf2(fmaxf(aa[2],0.f),  fmaxf(aa[3],0.f));
    u0.z = f2bf2(fmaxf(aa[4],0.f),  fmaxf(aa[5],0.f));
    u0.w = f2bf2(fmaxf(aa[6],0.f),  fmaxf(aa[7],0.f));
    u1.x = f2bf2(fmaxf(aa[8],0.f),  fmaxf(aa[9],0.f));
    u1.y = f2bf2(fmaxf(aa[10],0.f), fmaxf(aa[11],0.f));
    u1.z = f2bf2(fmaxf(aa[12],0.f), fmaxf(aa[13],0.f));
    u1.w = f2bf2(fmaxf(aa[14],0.f), fmaxf(aa[15],0.f));
    uint4* op = (uint4*)(hbout + (size_t)na * NDIM + ob);
    op[0] = u0; op[1] = u1;
  }
  if (nb < N) {
    uint4 u0, u1;
    u0.x = f2bf2(fmaxf(ab[0],0.f),  fmaxf(ab[1],0.f));
    u0.y = f2bf2(fmaxf(ab[2],0.f),  fmaxf(ab[3],0.f));
    u0.z = f2bf2(fmaxf(ab[4],0.f),  fmaxf(ab[5],0.f));
    u0.w = f2bf2(fmaxf(ab[6],0.f),  fmaxf(ab[7],0.f));
    u1.x = f2bf2(fmaxf(ab[8],0.f),  fmaxf(ab[9],0.f));
    u1.y = f2bf2(fmaxf(ab[10],0.f), fmaxf(ab[11],0.f));
    u1.z = f2bf2(fmaxf(ab[12],0.f), fmaxf(ab[13],0.f));
    u1.w = f2bf2(fmaxf(ab[14],0.f), fmaxf(ab[15],0.f));
    uint4* op = (uint4*)(hbout + (size_t)nb * NDIM + ob);
    op[0] = u0; op[1] = u1;
  }
}

// ---------------- final: 128-node bf16 LDS tiles (4 bufs), 2 nodes/lane ----------------

__global__ __launch_bounds__(256, 2) void final_kernel(
    const ushort* __restrict__ xB, const ushort* __restrict__ h1B,
    const ushort* __restrict__ h2B, const ushort* __restrict__ h3B,
    const float* __restrict__ fwT, const float* __restrict__ fb,
    float* __restrict__ outp, int N) {
  __shared__ uint Ft[4][128][33];
  int tid = threadIdx.x;
  int n0 = blockIdx.x * 128;
  {
    int r = tid >> 1, hf = tid & 1;
    int nc = min(n0 + r, N - 1);
    const ushort* bufs[4] = {xB, h1B, h2B, h3B};
#pragma unroll
    for (int b = 0; b < 4; ++b) {
      const uint4* ip = (const uint4*)(bufs[b] + (size_t)nc * 64);
#pragma unroll
      for (int i = 0; i < 4; ++i) {
        int q = hf * 4 + i;
        uint4 v = ip[q];
        int base = q * 4;
        Ft[b][r][base+0]=v.x; Ft[b][r][base+1]=v.y;
        Ft[b][r][base+2]=v.z; Ft[b][r][base+3]=v.w;
      }
    }
  }
  __syncthreads();
  int w = __builtin_amdgcn_readfirstlane(tid >> 6);
  int lane = tid & 63;
  int ob = w * 16;
  float aa[16], ab[16];
#pragma unroll
  for (int o = 0; o < 16; ++o) { float bv = fb[ob + o]; aa[o] = bv; ab[o] = bv; }
  for (int kp = 0; kp < 128; ++kp) {
    int buf = kp >> 5, kk = kp & 31;
    uint ua = Ft[buf][lane][kk], ub = Ft[buf][lane + 64][kk];
    float a0 = bflo(ua), a1 = bfhi(ua), b0 = bflo(ub), b1 = bfhi(ub);
    const float4* p0 = (const float4*)(fwT + (2 * kp) * 64 + ob);
    const float4* p1 = (const float4*)(fwT + (2 * kp + 1) * 64 + ob);
#pragma unroll
    for (int j = 0; j < 4; ++j) {
      float4 W0 = p0[j], W1 = p1[j];
      aa[4*j+0] += a0*W0.x + a1*W1.x;
      aa[4*j+1] += a0*W0.y + a1*W1.y;
      aa[4*j+2] += a0*W0.z + a1*W1.z;
      aa[4*j+3] += a0*W0.w + a1*W1.w;
      ab[4*j+0] += b0*W0.x + b1*W1.x;
      ab[4*j+1] += b0*W0.y + b1*W1.y;
      ab[4*j+2] += b0*W0.z + b1*W1.z;
      ab[4*j+3] += b0*W0.w + b1*W1.w;
    }
  }
  int na = n0 + lane, nb = n0 + 64 + lane;
  if (na < N) {
    float4* op = (float4*)(outp + (size_t)na * NDIM + ob);
#pragma unroll
    for (int j = 0; j < 4; ++j) {
      float4 v; v.x = aa[4*j+0]; v.y = aa[4*j+1]; v.z = aa[4*j+2]; v.w = aa[4*j+3];
      op[j] = v;
    }
  }
  if (nb < N) {
    float4* op = (float4*)(outp + (size_t)nb * NDIM + ob);
#pragma unroll
    for (int j = 0; j < 4; ++j) {
      float4 v; v.x = ab[4*j+0]; v.y = ab[4*j+1]; v.z = ab[4*j+2]; v.w = ab[4*j+3];
      op[j] = v;
    }
  }
}

// ---------------- launch ----------------

extern "C" void kernel_launch(void* const* d_in, const int* in_sizes, int n_in,
                              void* d_out, int out_size, void* d_ws, size_t ws_size,
                              hipStream_t stream) {
  const float* x     = (const float*)d_in[0];
  const int*   ei    = (const int*)d_in[1];
  const float* lin1  = (const float*)d_in[2];
  const float* lin2  = (const float*)d_in[3];
  const float* rootw = (const float*)d_in[4];
  const float* rootb = (const float*)d_in[5];
  const float* fw    = (const float*)d_in[6];
  const float* fb    = (const float*)d_in[7];
  float* out = (float*)d_out;

  int N = in_sizes[0] / NDIM;
  int E = in_sizes[1] / 2;
  const int* src = ei;
  const int* dst = ei + E;

  int* ip = (int*)d_ws;
  int* Hd    = ip; ip += (size_t)NCHK * N;
  int* Hs    = ip; ip += (size_t)NCHK * N;
  int* deg_d = ip; ip += N;
  int* deg_s = ip; ip += N;
  int* row_d = ip; ip += N + 1;
  int* row_s = ip; ip += N + 1;
  int* bsum  = ip; ip += 256;
  int* col_d = ip; ip += E;
  int* col_s = ip; ip += E;
  uintptr_t fbase = (((uintptr_t)ip) + 255) & ~(uintptr_t)255;
  float* fwT = (float*)fbase;
  float* wrT = fwT + 16384;
  float* w1T = wrT + 12288;
  float* w2T = w1T + 12288;
  ushort* hB0 = (ushort*)(w2T + 12288);
  ushort* hB1 = hB0 + (size_t)N * NDIM;
  ushort* hB2 = hB1 + (size_t)N * NDIM;
  ushort* hB3 = hB2 + (size_t)N * NDIM;
  ushort* g1b = hB3 + (size_t)N * NDIM;
  ushort* g2b = g1b + (size_t)N * NDIM;

  int chunk = (E + NCHK - 1) / NCHK;
  int nb = (N + SCAN_ELEMS - 1) / SCAN_ELEMS;
  int nblk = (N + 255) / 256;

  transpose_kernel<<<112, 256, 0, stream>>>(fw, rootw, lin1, lin2, fwT, wrT, w1T, w2T);
  convx_kernel<<<(N * 16 + 255) / 256, 256, 0, stream>>>(x, (uint*)hB0, N * 16);
  hist_kernel<<<dim3(NCHK, NGRP, 2), 256, 0, stream>>>(src, dst, Hd, Hs, E, N, chunk);
  degsum_kernel<<<nblk, 256, 0, stream>>>(Hd, Hs, deg_d, deg_s, N);
  scan_partial<<<dim3(nb, 2), 256, 0, stream>>>(deg_d, deg_s, bsum, N, nb);
  scan_bsum<<<1, 256, 0, stream>>>(bsum, nb);
  scan_final<<<dim3(nb, 2), 256, 0, stream>>>(deg_d, deg_s, bsum, row_d, row_s, N, nb);
  cursor_kernel<<<nblk, 256, 0, stream>>>(Hd, Hs, row_d, row_s, N);
  scatter_kernel<<<dim3(NGRP, NCHK, 2), 256, 0, stream>>>(src, dst, Hd, Hs,
                                                          col_d, col_s, E, N, chunk);

  int ab = (N + 3) / 4;
  int tgrid = (N + 127) / 128;
  ushort* hBufs[4] = {hB0, hB1, hB2, hB3};
  for (int l = 0; l < 3; ++l) {
    agg8_kernel<<<dim3(ab, 2), 256, 0, stream>>>(hBufs[l], row_d, col_d, g1b,
                                                 row_s, col_s, g2b, N);
    combine_kernel<<<tgrid, 256, 0, stream>>>(hBufs[l], g1b, g2b,
                                              wrT + (size_t)l * 4096,
                                              w1T + (size_t)l * 4096,
                                              w2T + (size_t)l * 4096,
                                              rootb + (size_t)l * 64,
                                              hBufs[l + 1], N);
  }
  final_kernel<<<tgrid, 256, 0, stream>>>(hB0, hB1, hB2, hB3, fwT, fb, out, N);
}

// Round 13
// 283.451 us; speedup vs baseline: 1.8396x; 1.0946x over previous
//
#include <hip/hip_runtime.h>
#include <stdint.h>

#define NDIM 64
#define SCAN_ELEMS 2048   // elements per scan block (256 thr x 8)
#define NCHK 32           // edge chunks
#define NGRP 8            // node-range groups
#define RMAX 6272         // max nodes per group (ceil(50000/8)=6250)

typedef unsigned int uint;
typedef unsigned short ushort;

// round-to-nearest-even fp32 -> bf16 (pair packed into a uint)
__device__ __forceinline__ uint f2bf2(float a, float b) {
  uint ua = __float_as_uint(a);
  uint ub = __float_as_uint(b);
  ua += 0x7fffu + ((ua >> 16) & 1u);
  ub += 0x7fffu + ((ub >> 16) & 1u);
  return (ua >> 16) | (ub & 0xffff0000u);
}
__device__ __forceinline__ float bflo(uint u) { return __uint_as_float(u << 16); }
__device__ __forceinline__ float bfhi(uint u) { return __uint_as_float(u & 0xffff0000u); }

// ---------------- weight transpose (k-major) ----------------
__global__ __launch_bounds__(256) void transpose_kernel(
    const float* __restrict__ fw, const float* __restrict__ rootw,
    const float* __restrict__ lin1, const float* __restrict__ lin2,
    float* __restrict__ fwT, float* __restrict__ wrT,
    float* __restrict__ w1T, float* __restrict__ w2T) {
  int e = blockIdx.x * 256 + threadIdx.x;
  if (e < 16384) {
    int o = e >> 8, k = e & 255;
    fwT[k * 64 + o] = fw[e];
  }
  int e2 = e - 16384;
  if (e2 >= 0 && e2 < 12288) {
    int l = e2 >> 12, r = e2 & 4095;
    int o = r >> 6, k = r & 63;
    size_t t = (size_t)l * 4096 + k * 64 + o;
    wrT[t] = rootw[e2];
    w1T[t] = lin1[e2];
    w2T[t] = lin2[e2];
  }
}

// ---------------- x -> bf16 table ----------------
__global__ __launch_bounds__(256) void convx_kernel(
    const float* __restrict__ x, uint* __restrict__ xb, int n4) {
  int e = blockIdx.x * 256 + threadIdx.x;
  if (e >= n4) return;
  float4 v = ((const float4*)x)[e];
  uint2 o;
  o.x = f2bf2(v.x, v.y);
  o.y = f2bf2(v.z, v.w);
  ((uint2*)xb)[e] = o;
}

// ---------------- CSR build: atomic-free chunked counting sort ----------------
__global__ __launch_bounds__(256) void hist_kernel(
    const int* __restrict__ src, const int* __restrict__ dst,
    int* __restrict__ Hd, int* __restrict__ Hs, int E, int N, int chunk) {
  int c = blockIdx.x, g = blockIdx.y, z = blockIdx.z;
  const int* key = z ? src : dst;
  int* H = z ? Hs : Hd;
  int lo = (int)((long long)N * g / NGRP);
  int hi = (int)((long long)N * (g + 1) / NGRP);
  int range = hi - lo;
  __shared__ int cnt[RMAX];
  for (int i = threadIdx.x; i < range; i += 256) cnt[i] = 0;
  __syncthreads();
  int e0 = c * chunk, e1 = min(E, e0 + chunk);
  for (int e = e0 + (int)threadIdx.x * 4; e < e1; e += 1024) {
    if (e + 4 <= e1) {
      int4 k4 = *(const int4*)(key + e);
      if (k4.x >= lo && k4.x < hi) atomicAdd(&cnt[k4.x - lo], 1);
      if (k4.y >= lo && k4.y < hi) atomicAdd(&cnt[k4.y - lo], 1);
      if (k4.z >= lo && k4.z < hi) atomicAdd(&cnt[k4.z - lo], 1);
      if (k4.w >= lo && k4.w < hi) atomicAdd(&cnt[k4.w - lo], 1);
    } else {
      for (int k = e; k < e1; ++k) {
        int v = key[k];
        if (v >= lo && v < hi) atomicAdd(&cnt[v - lo], 1);
      }
    }
  }
  __syncthreads();
  for (int i = threadIdx.x; i < range; i += 256)
    H[(size_t)c * N + lo + i] = cnt[i];
}

__global__ __launch_bounds__(256) void degsum_kernel(
    const int* __restrict__ Hd, const int* __restrict__ Hs,
    int* __restrict__ deg_d, int* __restrict__ deg_s, int N) {
  int n = blockIdx.x * 256 + threadIdx.x;
  if (n >= N) return;
  int sd = 0, ss = 0;
#pragma unroll
  for (int c = 0; c < NCHK; ++c) {
    sd += Hd[(size_t)c * N + n];
    ss += Hs[(size_t)c * N + n];
  }
  deg_d[n] = sd;
  deg_s[n] = ss;
}

__global__ __launch_bounds__(256) void scan_partial(
    const int* __restrict__ deg_d, const int* __restrict__ deg_s,
    int* __restrict__ bsum, int n, int nb) {
  const int* deg = (blockIdx.y == 0) ? deg_d : deg_s;
  int tid = threadIdx.x;
  int base = blockIdx.x * SCAN_ELEMS;
  int s = 0;
#pragma unroll
  for (int j = 0; j < 8; ++j) {
    int i = base + j * 256 + tid;
    if (i < n) s += deg[i];
  }
#pragma unroll
  for (int off = 1; off < 64; off <<= 1) s += __shfl_xor(s, off);
  __shared__ int ws[4];
  if ((tid & 63) == 0) ws[tid >> 6] = s;
  __syncthreads();
  if (tid == 0) bsum[blockIdx.y * nb + blockIdx.x] = ws[0] + ws[1] + ws[2] + ws[3];
}

__global__ __launch_bounds__(256) void scan_bsum(int* __restrict__ bsum, int nb) {
  __shared__ int sh[256];
  int tid = threadIdx.x;
  for (int h = 0; h < 2; ++h) {
    int v = (tid < nb) ? bsum[h * nb + tid] : 0;
    sh[tid] = v;
    __syncthreads();
    for (int off = 1; off < 256; off <<= 1) {
      int t = (tid >= off) ? sh[tid - off] : 0;
      __syncthreads();
      sh[tid] += t;
      __syncthreads();
    }
    if (tid < nb) bsum[h * nb + tid] = sh[tid] - v;  // exclusive
    __syncthreads();
  }
}

__global__ __launch_bounds__(256) void scan_final(
    const int* __restrict__ deg_d, const int* __restrict__ deg_s,
    const int* __restrict__ bsum,
    int* __restrict__ row_d, int* __restrict__ row_s, int n, int nb) {
  const int* deg = (blockIdx.y == 0) ? deg_d : deg_s;
  int* row = (blockIdx.y == 0) ? row_d : row_s;
  int tid = threadIdx.x;
  int lane = tid & 63;
  int e0 = blockIdx.x * SCAN_ELEMS + tid * 8;
  int v[8];
  int s = 0;
#pragma unroll
  for (int j = 0; j < 8; ++j) {
    int i = e0 + j;
    v[j] = (i < n) ? deg[i] : 0;
    s += v[j];
  }
  int incl = s;
#pragma unroll
  for (int off = 1; off < 64; off <<= 1) {
    int t = __shfl_up(incl, off);
    if (lane >= off) incl += t;
  }
  __shared__ int wsum[4];
  if (lane == 63) wsum[tid >> 6] = incl;
  __syncthreads();
  int woff = 0;
  int w = tid >> 6;
  for (int k = 0; k < 4; ++k)
    if (k < w) woff += wsum[k];
  int run = incl - s + woff + bsum[blockIdx.y * nb + blockIdx.x];
#pragma unroll
  for (int j = 0; j < 8; ++j) {
    int i = e0 + j;
    if (i <= n) row[i] = run;
    run += v[j];
  }
}

__global__ __launch_bounds__(256) void cursor_kernel(
    int* __restrict__ Hd, int* __restrict__ Hs,
    const int* __restrict__ row_d, const int* __restrict__ row_s, int N) {
  int n = blockIdx.x * 256 + threadIdx.x;
  if (n >= N) return;
  int rd = row_d[n], rs = row_s[n];
#pragma unroll
  for (int c = 0; c < NCHK; ++c) {
    int t = Hd[(size_t)c * N + n]; Hd[(size_t)c * N + n] = rd; rd += t;
    t = Hs[(size_t)c * N + n];     Hs[(size_t)c * N + n] = rs; rs += t;
  }
}

__global__ __launch_bounds__(256) void scatter_kernel(
    const int* __restrict__ src, const int* __restrict__ dst,
    const int* __restrict__ Hd, const int* __restrict__ Hs,
    int* __restrict__ col_d, int* __restrict__ col_s, int E, int N, int chunk) {
  int g = blockIdx.x, c = blockIdx.y, z = blockIdx.z;
  const int* key = z ? src : dst;
  const int* val = z ? dst : src;
  const int* H = z ? Hs : Hd;
  int* colp = z ? col_s : col_d;
  int lo = (int)((long long)N * g / NGRP);
  int hi = (int)((long long)N * (g + 1) / NGRP);
  int range = hi - lo;
  __shared__ int cur[RMAX];
  for (int i = threadIdx.x; i < range; i += 256)
    cur[i] = H[(size_t)c * N + lo + i];
  __syncthreads();
  int e0 = c * chunk, e1 = min(E, e0 + chunk);
  for (int e = e0 + (int)threadIdx.x * 4; e < e1; e += 1024) {
    if (e + 4 <= e1) {
      int4 k4 = *(const int4*)(key + e);
      int4 v4 = *(const int4*)(val + e);
      if (k4.x >= lo && k4.x < hi) { int p = atomicAdd(&cur[k4.x - lo], 1); colp[p] = v4.x; }
      if (k4.y >= lo && k4.y < hi) { int p = atomicAdd(&cur[k4.y - lo], 1); colp[p] = v4.y; }
      if (k4.z >= lo && k4.z < hi) { int p = atomicAdd(&cur[k4.z - lo], 1); colp[p] = v4.z; }
      if (k4.w >= lo && k4.w < hi) { int p = atomicAdd(&cur[k4.w - lo], 1); colp[p] = v4.w; }
    } else {
      for (int k = e; k < e1; ++k) {
        int kk = key[k], vv = val[k];
        if (kk >= lo && kk < hi) { int p = atomicAdd(&cur[kk - lo], 1); colp[p] = vv; }
      }
    }
  }
}

// ---------------- aggregation: 8 nodes per wave, NO cross-lane reduce --------------
// g = lane>>3 -> node slot, fl = lane&7 -> feature chunk. Each lane owns the
// [fl*8, fl*8+8) features of node (wv*8+g). One dwordx4 instr fetches one
// neighbor row for all 8 nodes. Degree divergence handled branch-free: loop
// to wave-max deg with 0/1 FMA weight and clamped col index.

#define FMA_ACC(A, U, W) {                                                   \
    A[0] += (W) * __uint_as_float((U).x << 16);                              \
    A[1] += (W) * __uint_as_float((U).x & 0xffff0000u);                      \
    A[2] += (W) * __uint_as_float((U).y << 16);                              \
    A[3] += (W) * __uint_as_float((U).y & 0xffff0000u);                      \
    A[4] += (W) * __uint_as_float((U).z << 16);                              \
    A[5] += (W) * __uint_as_float((U).z & 0xffff0000u);                      \
    A[6] += (W) * __uint_as_float((U).w << 16);                              \
    A[7] += (W) * __uint_as_float((U).w & 0xffff0000u); }

__global__ __launch_bounds__(256) void aggv_kernel(
    const ushort* __restrict__ hB,
    const int* __restrict__ row_d, const int* __restrict__ col_d, ushort* __restrict__ g1,
    const int* __restrict__ row_s, const int* __restrict__ col_s, ushort* __restrict__ g2,
    int N, int E) {
  const int* row = (blockIdx.y == 0) ? row_d : row_s;
  const int* col = (blockIdx.y == 0) ? col_d : col_s;
  ushort* outp = (blockIdx.y == 0) ? g1 : g2;
  int wv = blockIdx.x * 4 + (threadIdx.x >> 6);
  int lane = threadIdx.x & 63;
  int g = lane >> 3;
  int fl = lane & 7;
  int node = wv * 8 + g;
  int nc = min(node, N - 1);
  int s0 = row[nc], s1 = row[nc + 1];
  int d = s1 - s0;
  int dmax = d;
  dmax = max(dmax, __shfl_xor(dmax, 8));
  dmax = max(dmax, __shfl_xor(dmax, 16));
  dmax = max(dmax, __shfl_xor(dmax, 32));
  const ushort* tab = hB + fl * 8;
  float acc[8] = {0.f, 0.f, 0.f, 0.f, 0.f, 0.f, 0.f, 0.f};
  int i = 0;
  for (; i + 2 <= dmax; i += 2) {
    int p0 = s0 + i, p1 = s0 + i + 1;
    float w0 = p0 < s1 ? 1.f : 0.f;
    float w1 = p1 < s1 ? 1.f : 0.f;
    int n0 = col[min(p0, E - 1)];
    int n1 = col[min(p1, E - 1)];
    uint4 u0 = *(const uint4*)(tab + (size_t)n0 * 64);
    uint4 u1 = *(const uint4*)(tab + (size_t)n1 * 64);
    FMA_ACC(acc, u0, w0);
    FMA_ACC(acc, u1, w1);
  }
  if (i < dmax) {
    int p = s0 + i;
    float w = p < s1 ? 1.f : 0.f;
    int n = col[min(p, E - 1)];
    uint4 u = *(const uint4*)(tab + (size_t)n * 64);
    FMA_ACC(acc, u, w);
  }
  float inv = d > 0 ? 1.f / (float)d : 0.f;
  if (node < N) {
    uint4 o;
    o.x = f2bf2(acc[0] * inv, acc[1] * inv);
    o.y = f2bf2(acc[2] * inv, acc[3] * inv);
    o.z = f2bf2(acc[4] * inv, acc[5] * inv);
    o.w = f2bf2(acc[6] * inv, acc[7] * inv);
    *(uint4*)(outp + (size_t)node * NDIM + fl * 8) = o;
  }
}

// ---------------- combine: 128-node bf16 LDS tile, 2 nodes/lane, wave=16 outputs --------

__global__ __launch_bounds__(256, 3) void combine_kernel(
    const ushort* __restrict__ hBin, const ushort* __restrict__ g1b,
    const ushort* __restrict__ g2b, const float* __restrict__ wrT,
    const float* __restrict__ w1T, const float* __restrict__ w2T,
    const float* __restrict__ bias, ushort* __restrict__ hbout, int N) {
  __shared__ uint Ht[128][33];
  __shared__ uint G1t[128][33];
  __shared__ uint G2t[128][33];
  int tid = threadIdx.x;
  int n0 = blockIdx.x * 128;
  {
    int r = tid >> 1, hf = tid & 1;
    int nc = min(n0 + r, N - 1);
    const uint4* ph = (const uint4*)(hBin + (size_t)nc * 64);
    const uint4* p1 = (const uint4*)(g1b + (size_t)nc * 64);
    const uint4* p2 = (const uint4*)(g2b + (size_t)nc * 64);
#pragma unroll
    for (int i = 0; i < 4; ++i) {
      int q = hf * 4 + i;
      uint4 a = ph[q], b = p1[q], c = p2[q];
      int base = q * 4;
      Ht[r][base+0]=a.x;  Ht[r][base+1]=a.y;  Ht[r][base+2]=a.z;  Ht[r][base+3]=a.w;
      G1t[r][base+0]=b.x; G1t[r][base+1]=b.y; G1t[r][base+2]=b.z; G1t[r][base+3]=b.w;
      G2t[r][base+0]=c.x; G2t[r][base+1]=c.y; G2t[r][base+2]=c.z; G2t[r][base+3]=c.w;
    }
  }
  __syncthreads();
  int w = __builtin_amdgcn_readfirstlane(tid >> 6);
  int lane = tid & 63;
  int ob = w * 16;
  float aa[16], ab[16];
#pragma unroll
  for (int o = 0; o < 16; ++o) { float bv = bias[ob + o]; aa[o] = bv; ab[o] = bv; }
  for (int kp = 0; kp < 32; ++kp) {
    uint hua = Ht[lane][kp],  hub = Ht[lane + 64][kp];
    uint gua = G1t[lane][kp], gub = G1t[lane + 64][kp];
    uint fua = G2t[lane][kp], fub = G2t[lane + 64][kp];
    float ha0 = bflo(hua), ha1 = bfhi(hua), hb0 = bflo(hub), hb1 = bfhi(hub);
    float ga0 = bflo(gua), ga1 = bfhi(gua), gb0 = bflo(gub), gb1 = bfhi(gub);
    float fa0 = bflo(fua), fa1 = bfhi(fua), fb0 = bflo(fub), fb1 = bfhi(fub);
    const float4* pa0 = (const float4*)(wrT + (2 * kp) * 64 + ob);
    const float4* pa1 = (const float4*)(wrT + (2 * kp + 1) * 64 + ob);
    const float4* pb0 = (const float4*)(w1T + (2 * kp) * 64 + ob);
    const float4* pb1 = (const float4*)(w1T + (2 * kp + 1) * 64 + ob);
    const float4* pc0 = (const float4*)(w2T + (2 * kp) * 64 + ob);
    const float4* pc1 = (const float4*)(w2T + (2 * kp + 1) * 64 + ob);
#pragma unroll
    for (int j = 0; j < 4; ++j) {
      float4 A0 = pa0[j], A1 = pa1[j];
      float4 B0 = pb0[j], B1 = pb1[j];
      float4 C0 = pc0[j], C1 = pc1[j];
      aa[4*j+0] += ha0*A0.x + ha1*A1.x + ga0*B0.x + ga1*B1.x + fa0*C0.x + fa1*C1.x;
      aa[4*j+1] += ha0*A0.y + ha1*A1.y + ga0*B0.y + ga1*B1.y + fa0*C0.y + fa1*C1.y;
      aa[4*j+2] += ha0*A0.z + ha1*A1.z + ga0*B0.z + ga1*B1.z + fa0*C0.z + fa1*C1.z;
      aa[4*j+3] += ha0*A0.w + ha1*A1.w + ga0*B0.w + ga1*B1.w + fa0*C0.w + fa1*C1.w;
      ab[4*j+0] += hb0*A0.x + hb1*A1.x + gb0*B0.x + gb1*B1.x + fb0*C0.x + fb1*C1.x;
      ab[4*j+1] += hb0*A0.y + hb1*A1.y + gb0*B0.y + gb1*B1.y + fb0*C0.y + fb1*C1.y;
      ab[4*j+2] += hb0*A0.z + hb1*A1.z + gb0*B0.z + gb1*B1.z + fb0*C0.z + fb1*C1.z;
      ab[4*j+3] += hb0*A0.w + hb1*A1.w + gb0*B0.w + gb1*B1.w + fb0*C0.w + fb1*C1.w;
    }
  }
  int na = n0 + lane, nb = n0 + 64 + lane;
  if (na < N) {
    uint4 u0, u1;
    u0.x = f2bf2(fmaxf(aa[0],0.f),  fmaxf(aa[1],0.f));
    u0.y = f2bf2(fmaxf(aa[2],0.f),  fmaxf(aa[3],0.f));
    u0.z = f2bf2(fmaxf(aa[4],0.f),  fmaxf(aa[5],0.f));
    u0.w = f2bf2(fmaxf(aa[6],0.f),  fmaxf(aa[7],0.f));
    u1.x = f2bf2(fmaxf(aa[8],0.f),  fmaxf(aa[9],0.f));
    u1.y = f2bf2(fmaxf(aa[10],0.f), fmaxf(aa[11],0.f));
    u1.z = f2bf2(fmaxf(aa[12],0.f), fmaxf(aa[13],0.f));
    u1.w = f2bf2(fmaxf(aa[14],0.f), fmaxf(aa[15],0.f));
    uint4* op = (uint4*)(hbout + (size_t)na * NDIM + ob);
    op[0] = u0; op[1] = u1;
  }
  if (nb < N) {
    uint4 u0, u1;
    u0.x = f2bf2(fmaxf(ab[0],0.f),  fmaxf(ab[1],0.f));
    u0.y = f2bf2(fmaxf(ab[2],0.f),  fmaxf(ab[3],0.f));
    u0.z = f2bf2(fmaxf(ab[4],0.f),  fmaxf(ab[5],0.f));
    u0.w = f2bf2(fmaxf(ab[6],0.f),  fmaxf(ab[7],0.f));
    u1.x = f2bf2(fmaxf(ab[8],0.f),  fmaxf(ab[9],0.f));
    u1.y = f2bf2(fmaxf(ab[10],0.f), fmaxf(ab[11],0.f));
    u1.z = f2bf2(fmaxf(ab[12],0.f), fmaxf(ab[13],0.f));
    u1.w = f2bf2(fmaxf(ab[14],0.f), fmaxf(ab[15],0.f));
    uint4* op = (uint4*)(hbout + (size_t)nb * NDIM + ob);
    op[0] = u0; op[1] = u1;
  }
}

// ---------------- final: 128-node bf16 LDS tiles (4 bufs), 2 nodes/lane ----------------

__global__ __launch_bounds__(256, 2) void final_kernel(
    const ushort* __restrict__ xB, const ushort* __restrict__ h1B,
    const ushort* __restrict__ h2B, const ushort* __restrict__ h3B,
    const float* __restrict__ fwT, const float* __restrict__ fb,
    float* __restrict__ outp, int N) {
  __shared__ uint Ft[4][128][33];
  int tid = threadIdx.x;
  int n0 = blockIdx.x * 128;
  {
    int r = tid >> 1, hf = tid & 1;
    int nc = min(n0 + r, N - 1);
    const ushort* bufs[4] = {xB, h1B, h2B, h3B};
#pragma unroll
    for (int b = 0; b < 4; ++b) {
      const uint4* ip = (const uint4*)(bufs[b] + (size_t)nc * 64);
#pragma unroll
      for (int i = 0; i < 4; ++i) {
        int q = hf * 4 + i;
        uint4 v = ip[q];
        int base = q * 4;
        Ft[b][r][base+0]=v.x; Ft[b][r][base+1]=v.y;
        Ft[b][r][base+2]=v.z; Ft[b][r][base+3]=v.w;
      }
    }
  }
  __syncthreads();
  int w = __builtin_amdgcn_readfirstlane(tid >> 6);
  int lane = tid & 63;
  int ob = w * 16;
  float aa[16], ab[16];
#pragma unroll
  for (int o = 0; o < 16; ++o) { float bv = fb[ob + o]; aa[o] = bv; ab[o] = bv; }
  for (int kp = 0; kp < 128; ++kp) {
    int buf = kp >> 5, kk = kp & 31;
    uint ua = Ft[buf][lane][kk], ub = Ft[buf][lane + 64][kk];
    float a0 = bflo(ua), a1 = bfhi(ua), b0 = bflo(ub), b1 = bfhi(ub);
    const float4* p0 = (const float4*)(fwT + (2 * kp) * 64 + ob);
    const float4* p1 = (const float4*)(fwT + (2 * kp + 1) * 64 + ob);
#pragma unroll
    for (int j = 0; j < 4; ++j) {
      float4 W0 = p0[j], W1 = p1[j];
      aa[4*j+0] += a0*W0.x + a1*W1.x;
      aa[4*j+1] += a0*W0.y + a1*W1.y;
      aa[4*j+2] += a0*W0.z + a1*W1.z;
      aa[4*j+3] += a0*W0.w + a1*W1.w;
      ab[4*j+0] += b0*W0.x + b1*W1.x;
      ab[4*j+1] += b0*W0.y + b1*W1.y;
      ab[4*j+2] += b0*W0.z + b1*W1.z;
      ab[4*j+3] += b0*W0.w + b1*W1.w;
    }
  }
  int na = n0 + lane, nb = n0 + 64 + lane;
  if (na < N) {
    float4* op = (float4*)(outp + (size_t)na * NDIM + ob);
#pragma unroll
    for (int j = 0; j < 4; ++j) {
      float4 v; v.x = aa[4*j+0]; v.y = aa[4*j+1]; v.z = aa[4*j+2]; v.w = aa[4*j+3];
      op[j] = v;
    }
  }
  if (nb < N) {
    float4* op = (float4*)(outp + (size_t)nb * NDIM + ob);
#pragma unroll
    for (int j = 0; j < 4; ++j) {
      float4 v; v.x = ab[4*j+0]; v.y = ab[4*j+1]; v.z = ab[4*j+2]; v.w = ab[4*j+3];
      op[j] = v;
    }
  }
}

// ---------------- launch ----------------

extern "C" void kernel_launch(void* const* d_in, const int* in_sizes, int n_in,
                              void* d_out, int out_size, void* d_ws, size_t ws_size,
                              hipStream_t stream) {
  const float* x     = (const float*)d_in[0];
  const int*   ei    = (const int*)d_in[1];
  const float* lin1  = (const float*)d_in[2];
  const float* lin2  = (const float*)d_in[3];
  const float* rootw = (const float*)d_in[4];
  const float* rootb = (const float*)d_in[5];
  const float* fw    = (const float*)d_in[6];
  const float* fb    = (const float*)d_in[7];
  float* out = (float*)d_out;

  int N = in_sizes[0] / NDIM;
  int E = in_sizes[1] / 2;
  const int* src = ei;
  const int* dst = ei + E;

  int* ip = (int*)d_ws;
  int* Hd    = ip; ip += (size_t)NCHK * N;
  int* Hs    = ip; ip += (size_t)NCHK * N;
  int* deg_d = ip; ip += N;
  int* deg_s = ip; ip += N;
  int* row_d = ip; ip += N + 1;
  int* row_s = ip; ip += N + 1;
  int* bsum  = ip; ip += 256;
  int* col_d = ip; ip += E;
  int* col_s = ip; ip += E;
  uintptr_t fbase = (((uintptr_t)ip) + 255) & ~(uintptr_t)255;
  float* fwT = (float*)fbase;
  float* wrT = fwT + 16384;
  float* w1T = wrT + 12288;
  float* w2T = w1T + 12288;
  ushort* hB0 = (ushort*)(w2T + 12288);
  ushort* hB1 = hB0 + (size_t)N * NDIM;
  ushort* hB2 = hB1 + (size_t)N * NDIM;
  ushort* hB3 = hB2 + (size_t)N * NDIM;
  ushort* g1b = hB3 + (size_t)N * NDIM;
  ushort* g2b = g1b + (size_t)N * NDIM;

  int chunk = (E + NCHK - 1) / NCHK;
  int nb = (N + SCAN_ELEMS - 1) / SCAN_ELEMS;
  int nblk = (N + 255) / 256;

  transpose_kernel<<<112, 256, 0, stream>>>(fw, rootw, lin1, lin2, fwT, wrT, w1T, w2T);
  convx_kernel<<<(N * 16 + 255) / 256, 256, 0, stream>>>(x, (uint*)hB0, N * 16);
  hist_kernel<<<dim3(NCHK, NGRP, 2), 256, 0, stream>>>(src, dst, Hd, Hs, E, N, chunk);
  degsum_kernel<<<nblk, 256, 0, stream>>>(Hd, Hs, deg_d, deg_s, N);
  scan_partial<<<dim3(nb, 2), 256, 0, stream>>>(deg_d, deg_s, bsum, N, nb);
  scan_bsum<<<1, 256, 0, stream>>>(bsum, nb);
  scan_final<<<dim3(nb, 2), 256, 0, stream>>>(deg_d, deg_s, bsum, row_d, row_s, N, nb);
  cursor_kernel<<<nblk, 256, 0, stream>>>(Hd, Hs, row_d, row_s, N);
  scatter_kernel<<<dim3(NGRP, NCHK, 2), 256, 0, stream>>>(src, dst, Hd, Hs,
                                                          col_d, col_s, E, N, chunk);

  int avgrid = (N + 31) / 32;    // 4 waves x 8 nodes per block
  int tgrid = (N + 127) / 128;
  ushort* hBufs[4] = {hB0, hB1, hB2, hB3};
  for (int l = 0; l < 3; ++l) {
    aggv_kernel<<<dim3(avgrid, 2), 256, 0, stream>>>(hBufs[l], row_d, col_d, g1b,
                                                     row_s, col_s, g2b, N, E);
    combine_kernel<<<tgrid, 256, 0, stream>>>(hBufs[l], g1b, g2b,
                                              wrT + (size_t)l * 4096,
                                              w1T + (size_t)l * 4096,
                                              w2T + (size_t)l * 4096,
                                              rootb + (size_t)l * 64,
                                              hBufs[l + 1], N);
  }
  final_kernel<<<tgrid, 256, 0, stream>>>(hB0, hB1, hB2, hB3, fwT, fb, out, N);
}